// Round 4
// baseline (195.192 us; speedup 1.0000x reference)
//
#include <hip/hip_runtime.h>
#include <math.h>

#define NPOS 2304   // 48*48
#define CC   256    // DIM
#define DI   512    // HEADS*DIM_HEAD
#define NT   36     // NPOS/64
#define SCALE 0.125f
#define MASKV -100.0f
// exp(-SCALE*sqrt(d2)) = exp2(-SCALE*log2(e)*sqrt(d2))
#define NEGSL2E (-0.18033688011112042f)

typedef __attribute__((ext_vector_type(8))) short bf16x8;  // 8 bf16 (4 VGPRs)
typedef __attribute__((ext_vector_type(4))) float f32x4;   // MFMA C/D frag
typedef unsigned short u16;
typedef unsigned int u32;

__device__ inline u16 f2bf(float f) {
    union { float f; unsigned int u; } v; v.f = f;
    return (u16)((v.u + 0x7fffu + ((v.u >> 16) & 1u)) >> 16);
}
__device__ inline float bf2f(u16 h) { return __uint_as_float(((u32)h) << 16); }

// assemble a bf16x8 frag from 8-byte-aligned LDS via two b64 reads
__device__ inline bf16x8 ld_x8(const u16* p) {
    union { bf16x8 v; uint2 d[2]; } u;
    u.d[0] = *(const uint2*)(p + 0);
    u.d[1] = *(const uint2*)(p + 4);
    return u.v;
}

// ---------------- Kernel 1: fused rmsnorm + paired qk/v MFMA projection ----------------
// XCD-aligned 1D grid: blk<576 -> xcd=blk&7 produces bh=xcd*2+(r&1), matching
// k_attn's consumer swizzle so each (b,h)'s qkh/vt/sq/ndot sit in the local L2.
// blk in [576,648): one-time w_out hi/lo split.
__global__ __launch_bounds__(256) void k_proj(const float* __restrict__ fmap,
                                              const float* __restrict__ gamma,
                                              const float* __restrict__ wqk,
                                              const float* __restrict__ wv,
                                              const float* __restrict__ wout,
                                              const float* __restrict__ null_kv,
                                              u16* __restrict__ qkh,
                                              u16* __restrict__ vt,
                                              float* __restrict__ sq,
                                              float* __restrict__ ndot,
                                              float* __restrict__ nk2b,
                                              u16* __restrict__ wo_hi,
                                              u16* __restrict__ wo_lo) {
    const int blk = blockIdx.x;
    if (blk >= 576) {                     // w_out hi/lo split (no LDS use, early out)
        const int idx = blk - 576;        // 0..71
#pragma unroll
        for (int it = 0; it < 2; ++it) {
            const int k = idx * 512 + (int)threadIdx.x + it * 256;
            if (k < 32768) {
                const float4 v = ((const float4*)wout)[k];
                ushort4 h4, l4;
                h4.x = f2bf(v.x); l4.x = f2bf(v.x - bf2f(h4.x));
                h4.y = f2bf(v.y); l4.y = f2bf(v.y - bf2f(h4.y));
                h4.z = f2bf(v.z); l4.z = f2bf(v.z - bf2f(h4.z));
                h4.w = f2bf(v.w); l4.w = f2bf(v.w - bf2f(h4.w));
                ((ushort4*)wo_hi)[k] = h4;
                ((ushort4*)wo_lo)[k] = l4;
            }
        }
        return;
    }
    // XCD-aligned decode: bh pair per XCD matches k_attn (bh = xcd*2 + parity)
    const int xcd = blk & 7;
    const int r   = blk >> 3;             // 0..71
    const int bh  = xcd * 2 + (r & 1);    // 0..15
    const int b   = bh >> 3;
    const int oy  = bh & 7;               // head
    const int n0  = (r >> 1) * 64;        // 36 position tiles

    const int t  = threadIdx.x;
    const int w = t >> 6, lane = t & 63, mcol = lane & 15, quad = lane >> 4;
    const int tx = t & 63, ty = t >> 6;

    __shared__ u16 X[64][260];            // [pos][chan]; dword pitch 130, rows 8B-aligned
    __shared__ float red[4][64];
    __shared__ float inv_s[64];
    __shared__ float gs[256];
    __shared__ float sqp[4][64], ndp[4][64];
    u16 (*Tt)[68] = (u16(*)[68])X;        // aliased after phase B

    // ---- phase A: rmsnorm, fmap held in registers (single global pass) ----
    gs[t] = gamma[t];
    const float* fb = fmap + (size_t)b * CC * NPOS;
    float v64[64];
#pragma unroll
    for (int i = 0; i < 64; ++i)
        v64[i] = fb[(ty * 64 + i) * NPOS + n0 + tx];
    float s = 0.0f;
#pragma unroll
    for (int i = 0; i < 64; ++i) s += v64[i] * v64[i];
    red[ty][tx] = s;
    __syncthreads();
    if (t < 64) {
        const float tt = red[0][t] + red[1][t] + red[2][t] + red[3][t];
        inv_s[t] = 16.0f / fmaxf(sqrtf(tt), 1e-12f);
    }
    __syncthreads();
    const float iv = inv_s[tx];
#pragma unroll
    for (int i = 0; i < 64; i += 2) {
        const int c = ty * 64 + i;
        const float v0 = v64[i] * iv * gs[c];
        const float v1 = v64[i + 1] * iv * gs[c + 1];
        *(u32*)&X[tx][c] = (u32)f2bf(v0) | ((u32)f2bf(v1) << 16);   // bank 2-way: free
    }
    if (blk == 0 && t < 8) {
        float s2 = 0.0f;
#pragma unroll 8
        for (int d = 0; d < 64; ++d) { const float x = null_kv[t * 64 + d]; s2 += x * x; }
        nk2b[t] = s2;
    }
    __syncthreads();

    // ---- phase B (dual): one X frag read feeds qk-head AND v-head MFMA ----
    const size_t wroff = (size_t)(oy * 64 + w * 16 + mcol) * 256 + quad * 8;
    const float* wrq = wqk + wroff;
    const float* wrv = wv + wroff;

    f32x4 cq[4], cv[4];
#pragma unroll
    for (int nf = 0; nf < 4; ++nf) {
        cq[nf] = (f32x4){0.f, 0.f, 0.f, 0.f};
        cv[nf] = (f32x4){0.f, 0.f, 0.f, 0.f};
    }
#pragma unroll
    for (int kc = 0; kc < 8; ++kc) {
        const float4 qa = *(const float4*)&wrq[kc * 32];
        const float4 qb4 = *(const float4*)&wrq[kc * 32 + 4];
        const float4 va = *(const float4*)&wrv[kc * 32];
        const float4 vb4 = *(const float4*)&wrv[kc * 32 + 4];
        bf16x8 aq, av;
        aq[0] = f2bf(qa.x);  aq[1] = f2bf(qa.y);  aq[2] = f2bf(qa.z);  aq[3] = f2bf(qa.w);
        aq[4] = f2bf(qb4.x); aq[5] = f2bf(qb4.y); aq[6] = f2bf(qb4.z); aq[7] = f2bf(qb4.w);
        av[0] = f2bf(va.x);  av[1] = f2bf(va.y);  av[2] = f2bf(va.z);  av[3] = f2bf(va.w);
        av[4] = f2bf(vb4.x); av[5] = f2bf(vb4.y); av[6] = f2bf(vb4.z); av[7] = f2bf(vb4.w);
        bf16x8 xB[4];
#pragma unroll
        for (int nf = 0; nf < 4; ++nf)
            xB[nf] = ld_x8(&X[nf * 16 + mcol][kc * 32 + quad * 8]);
#pragma unroll
        for (int nf = 0; nf < 4; ++nf) {
            cq[nf] = __builtin_amdgcn_mfma_f32_16x16x32_bf16(aq, xB[nf], cq[nf], 0, 0, 0);
            cv[nf] = __builtin_amdgcn_mfma_f32_16x16x32_bf16(av, xB[nf], cv[nf], 0, 0, 0);
        }
    }
    __syncthreads();   // all X reads done; Tt alias safe

    // ---- epilogue 1: qk head -> qkh + sq/ndot ----
    {
        const int h = oy;   // d = w*16 + quad*4 + r, n = n0 + nf*16 + mcol
        const float4 nk4 = *(const float4*)&null_kv[h * 64 + w * 16 + quad * 4];
        float sv[4], nd[4];
#pragma unroll
        for (int nf = 0; nf < 4; ++nf) {
            sv[nf] = cq[nf][0] * cq[nf][0] + cq[nf][1] * cq[nf][1] + cq[nf][2] * cq[nf][2] + cq[nf][3] * cq[nf][3];
            nd[nf] = cq[nf][0] * nk4.x + cq[nf][1] * nk4.y + cq[nf][2] * nk4.z + cq[nf][3] * nk4.w;
        }
#pragma unroll
        for (int mk = 16; mk <= 32; mk <<= 1)
#pragma unroll
            for (int nf = 0; nf < 4; ++nf) {
                sv[nf] += __shfl_xor(sv[nf], mk);
                nd[nf] += __shfl_xor(nd[nf], mk);
            }
        if (quad == 0) {
#pragma unroll
            for (int nf = 0; nf < 4; ++nf) {
                sqp[w][nf * 16 + mcol] = sv[nf];
                ndp[w][nf * 16 + mcol] = nd[nf];
            }
        }
#pragma unroll
        for (int nf = 0; nf < 4; ++nf) {
            ushort4 r4;
            r4.x = f2bf(cq[nf][0]); r4.y = f2bf(cq[nf][1]);
            r4.z = f2bf(cq[nf][2]); r4.w = f2bf(cq[nf][3]);
            *(ushort4*)&Tt[nf * 16 + mcol][w * 16 + quad * 4] = r4;   // Tt[n][d]
        }
        __syncthreads();
        {
            const int n = t >> 2, ds = (t & 3) * 16;
            const uint2 r0 = *(const uint2*)&Tt[n][ds + 0];
            const uint2 r1 = *(const uint2*)&Tt[n][ds + 4];
            const uint2 r2 = *(const uint2*)&Tt[n][ds + 8];
            const uint2 r3 = *(const uint2*)&Tt[n][ds + 12];
            u16* dst = qkh + (((size_t)bh) * NPOS + n0 + n) * 64 + ds;
            *(uint4*)&dst[0] = make_uint4(r0.x, r0.y, r1.x, r1.y);
            *(uint4*)&dst[8] = make_uint4(r2.x, r2.y, r3.x, r3.y);
        }
        if (t < 64) {
            sq  [((size_t)bh) * NPOS + n0 + t] = sqp[0][t] + sqp[1][t] + sqp[2][t] + sqp[3][t];
            ndot[((size_t)bh) * NPOS + n0 + t] = ndp[0][t] + ndp[1][t] + ndp[2][t] + ndp[3][t];
        }
    }
    __syncthreads();   // qk readback done before Tt reuse

    // ---- epilogue 2: v head -> vt frag-ordered ----
    {
#pragma unroll
        for (int nf = 0; nf < 4; ++nf)
#pragma unroll
            for (int rr = 0; rr < 4; ++rr)
                Tt[w * 16 + quad * 4 + rr][nf * 16 + mcol] = f2bf(cv[nf][rr]);  // Tt[d][key]
        __syncthreads();
        {
            const int d = t >> 2, ks = t & 3;
            const uint2 a0 = *(const uint2*)&Tt[d][ks * 16 + 0];
            const uint2 a1 = *(const uint2*)&Tt[d][ks * 16 + 4];
            const uint2 a2 = *(const uint2*)&Tt[d][ks * 16 + 8];
            const uint2 a3 = *(const uint2*)&Tt[d][ks * 16 + 12];
            u16* vdst = vt + (size_t)bh * (72 * 64 * 32);
            const int kb = (n0 >> 5) + (ks >> 1);
            u16* p = &vdst[((size_t)kb * 64 + d) * 32 + (ks & 1) * 16];
            *(uint4*)&p[0] = make_uint4(a0.x, a0.y, a1.x, a1.y);
            *(uint4*)&p[8] = make_uint4(a2.x, a2.y, a3.x, a3.y);
        }
    }
}

// ---------------- Kernel 2: LDS-staged MFMA flash attention, 64 q/block ----------------
// R16: restructure for K/V L2-traffic reuse. R2's 16q run was a clean traffic
// experiment: dur ≈ 34 µs fixed + L2_traffic / 17 TB/s (83 µs @ 830 MB,
// 131 µs @ 1.66 GB). The old decomposition (waves split k, 72 q-blocks per bh)
// re-reads the full 588 KB K+V per q-block. New: grid 576 = 16 bh x 36 q64
// tiles; waves split q (16 each, complete rows); K/V staged per k-tile into
// double-buffered LDS shared by all 4 waves -> traffic halves AND hot loads
// move from ~200cy L2 to LDS. Reg-staged (padded LDS rows kill the stride-128B
// bank conflict); next-tile global loads issued right after the barrier so L2
// latency hides under a full tile of compute (T14). One barrier per tile:
// iter reads buf[p], writes buf[p^1] (readers of p^1 finished pre-barrier).
// Cross-wave merge phase deleted (waves own complete queries). No setprio
// (lockstep-barrier regime = m190 null).
__global__ __launch_bounds__(256) void k_attn(const u16* __restrict__ qkh,
                                              const u16* __restrict__ vt,
                                              const float* __restrict__ null_kv,
                                              const float* __restrict__ nk2b,
                                              const float* __restrict__ sq,
                                              const float* __restrict__ ndot,
                                              u16* __restrict__ ih,
                                              u16* __restrict__ il) {
    const int blk = blockIdx.x;             // 576
    const int xcd = blk & 7;
    const int j = blk >> 3;                 // 0..71
    const int bh = xcd * 2 + (j & 1);       // XCD-local bh pair
    const int qt = j >> 1;                  // 0..35
    const int q0 = qt * 64;
    const int b = bh >> 3, h = bh & 7;
    const int t = threadIdx.x;
    const int wave = t >> 6, lane = t & 63;
    const int mcol = lane & 15, quad = lane >> 4;

    // K: [buf][64 keys][72 u16]  (64 data + 8 pad; rows 144B, 16B-aligned)
    // V: [buf][2 sub][64 d][36 u16] (32 data + 4 pad; rows 72B, 8B-aligned)
    __shared__ __align__(16) u16 Kl[2][4608];
    __shared__ __align__(16) u16 Vl[2][4608];
    __shared__ __align__(16) u16 Ptl[4][16][72];

    const u16* qbase = qkh + (size_t)bh * NPOS * 64;
    const u16* vbase = vt + (size_t)bh * (72 * 64 * 32);
    const float* sqb = sq + (size_t)bh * NPOS;

    const int q16 = q0 + wave * 16;
    const bf16x8 bq00 = *(const bf16x8*)&qbase[(q16 + mcol) * 64 + quad * 8];
    const bf16x8 bq01 = *(const bf16x8*)&qbase[(q16 + mcol) * 64 + 32 + quad * 8];
    const float q2 = sqb[q16 + mcol];
    const int ktm = q16 >> 6;               // k-tile containing the self-masked key
    const int nbm = (q16 >> 4) & 3;

    u16 (*Pt)[72] = Ptl[wave];

    // staging addresses (per thread): K row = key, V row = d
    const int kdst = (t >> 2) * 72 + (t & 3) * 16;
    const int vdst = (t >> 7) * 2304 + ((t & 127) >> 1) * 36 + (t & 1) * 16;

    uint4 kr0, kr1, vr0, vr1;
    {   // prologue: stage tile 0 into buf 0
        const uint4* ks = (const uint4*)qbase;
        const uint4* vs = (const uint4*)vbase;
        kr0 = ks[t * 2]; kr1 = ks[t * 2 + 1];
        vr0 = vs[t * 2]; vr1 = vs[t * 2 + 1];
        *(uint4*)&Kl[0][kdst] = kr0; *(uint4*)&Kl[0][kdst + 8] = kr1;
        *(uint4*)&Vl[0][vdst] = vr0; *(uint4*)&Vl[0][vdst + 8] = vr1;
    }

    const bf16x8 ones = {0x3F80, 0x3F80, 0x3F80, 0x3F80, 0x3F80, 0x3F80, 0x3F80, 0x3F80};

    f32x4 oacc[4];
#pragma unroll
    for (int nb = 0; nb < 4; ++nb) oacc[nb] = (f32x4){0.f, 0.f, 0.f, 0.f};
    f32x4 lsum = (f32x4){0.f, 0.f, 0.f, 0.f};

    int p = 0;
#pragma unroll 1
    for (int kt = 0; kt < 36; ++kt) {
        __syncthreads();                    // buf[p] staged & visible
        // issue next tile's global loads early (hide L2 latency under compute)
        if (kt + 1 < 36) {
            const uint4* ks = (const uint4*)(qbase + (size_t)(kt + 1) * 4096);
            const uint4* vs = (const uint4*)(vbase + (size_t)(kt + 1) * 4096);
            kr0 = ks[t * 2]; kr1 = ks[t * 2 + 1];
            vr0 = vs[t * 2]; vr1 = vs[t * 2 + 1];
        }
        float4 k2q[4];
#pragma unroll
        for (int nb = 0; nb < 4; ++nb)
            k2q[nb] = *(const float4*)&sqb[kt * 64 + nb * 16 + quad * 4];

        const u16* Kb = Kl[p];
        const u16* Vb = Vl[p];

        bf16x8 bk[4][2];
#pragma unroll
        for (int nb = 0; nb < 4; ++nb) {
            const u16* krw = &Kb[(nb * 16 + mcol) * 72 + quad * 8];
            bk[nb][0] = *(const bf16x8*)&krw[0];
            bk[nb][1] = *(const bf16x8*)&krw[32];
        }

        f32x4 c[4];
#pragma unroll
        for (int nb = 0; nb < 4; ++nb) {
            c[nb] = (f32x4){0.f, 0.f, 0.f, 0.f};
            c[nb] = __builtin_amdgcn_mfma_f32_16x16x32_bf16(bk[nb][0], bq00, c[nb], 0, 0, 0);
            c[nb] = __builtin_amdgcn_mfma_f32_16x16x32_bf16(bk[nb][1], bq01, c[nb], 0, 0, 0);
        }

        bf16x8 bv[4][2];
#pragma unroll
        for (int nb = 0; nb < 4; ++nb) {
            bv[nb][0] = ld_x8(&Vb[(nb * 16 + mcol) * 36 + quad * 8]);
            bv[nb][1] = ld_x8(&Vb[2304 + (nb * 16 + mcol) * 36 + quad * 8]);
        }

#pragma unroll
        for (int nb = 0; nb < 4; ++nb) {
            float e[4];
#pragma unroll
            for (int r = 0; r < 4; ++r) {
                const float pre = q2 + ((const float*)&k2q[nb])[r];
                const float d2 = fmaxf(__builtin_fmaf(c[nb][r], -2.0f, pre), 0.0f);
                e[r] = __builtin_amdgcn_exp2f(NEGSL2E * __builtin_amdgcn_sqrtf(d2));
            }
            if (kt == ktm && nb == nbm) {
#pragma unroll
                for (int r = 0; r < 4; ++r)
                    if (quad * 4 + r == mcol) e[r] = 0.0f;   // exp(MASKV) ~ 0
            }
            const u32 p01 = __builtin_amdgcn_perm(__float_as_uint(e[1]), __float_as_uint(e[0]), 0x07060302u);
            const u32 p23 = __builtin_amdgcn_perm(__float_as_uint(e[3]), __float_as_uint(e[2]), 0x07060302u);
            *(uint2*)&Pt[mcol][nb * 16 + quad * 4] = make_uint2(p01, p23);
        }

        const bf16x8 bp00 = *(const bf16x8*)&Pt[mcol][quad * 8];
        const bf16x8 bp01 = *(const bf16x8*)&Pt[mcol][32 + quad * 8];

#pragma unroll
        for (int nb = 0; nb < 4; ++nb) {
            oacc[nb] = __builtin_amdgcn_mfma_f32_16x16x32_bf16(bv[nb][0], bp00, oacc[nb], 0, 0, 0);
            oacc[nb] = __builtin_amdgcn_mfma_f32_16x16x32_bf16(bv[nb][1], bp01, oacc[nb], 0, 0, 0);
        }
        lsum = __builtin_amdgcn_mfma_f32_16x16x32_bf16(ones, bp00, lsum, 0, 0, 0);
        lsum = __builtin_amdgcn_mfma_f32_16x16x32_bf16(ones, bp01, lsum, 0, 0, 0);

        // write next tile into the other buffer (readers of p^1 finished
        // before this iteration's barrier)
        if (kt + 1 < 36) {
            u16* kd = &Kl[p ^ 1][kdst];
            *(uint4*)kd = kr0; *(uint4*)(kd + 8) = kr1;
            u16* vd = &Vl[p ^ 1][vdst];
            *(uint4*)vd = vr0; *(uint4*)(vd + 8) = vr1;
        }
        p ^= 1;
    }

    __syncthreads();                        // main loop done; Kl reusable

    // ---- per-wave finalize: transpose via LDS (alias Kl), no cross-wave merge ----
    float* Ofin = (float*)&Kl[0][0] + wave * (16 * 68);   // [16 q][68 f32]
#pragma unroll
    for (int nb = 0; nb < 4; ++nb)
        *(f32x4*)&Ofin[mcol * 68 + nb * 16 + quad * 4] = oacc[nb];
    if (quad == 0) Ofin[mcol * 68 + 64] = lsum[0];

    {
        const int q = lane >> 2;            // 0..15
        const int d0 = (lane & 3) * 16;     // 0, 16, 32, 48
        const float4 a0 = *(const float4*)&Ofin[q * 68 + d0 + 0];
        const float4 a1 = *(const float4*)&Ofin[q * 68 + d0 + 4];
        const float4 a2 = *(const float4*)&Ofin[q * 68 + d0 + 8];
        const float4 a3 = *(const float4*)&Ofin[q * 68 + d0 + 12];
        const float l = Ofin[q * 68 + 64];

        const int qg = q16 + q;
        const float q2v = sqb[qg];
        const float nd = ndot[(size_t)bh * NPOS + qg];
        const float nk2 = nk2b[h];
        const float d2n = fmaxf(q2v + nk2 - 2.0f * nd, 0.0f);
        const float beta = __expf(-sqrtf(d2n) * SCALE);
        const float ilv = 1.0f / (l + beta);

        const float* nvp = &null_kv[DI + h * 64 + d0];
        const float4 nv0 = *(const float4*)&nvp[0];
        const float4 nv1 = *(const float4*)&nvp[4];
        const float4 nv2 = *(const float4*)&nvp[8];
        const float4 nv3 = *(const float4*)&nvp[12];

        const size_t ob = ((size_t)b * NPOS + qg) * DI + h * 64 + d0;
        float vv[16];
        vv[0]  = (a0.x + beta * nv0.x) * ilv; vv[1]  = (a0.y + beta * nv0.y) * ilv;
        vv[2]  = (a0.z + beta * nv0.z) * ilv; vv[3]  = (a0.w + beta * nv0.w) * ilv;
        vv[4]  = (a1.x + beta * nv1.x) * ilv; vv[5]  = (a1.y + beta * nv1.y) * ilv;
        vv[6]  = (a1.z + beta * nv1.z) * ilv; vv[7]  = (a1.w + beta * nv1.w) * ilv;
        vv[8]  = (a2.x + beta * nv2.x) * ilv; vv[9]  = (a2.y + beta * nv2.y) * ilv;
        vv[10] = (a2.z + beta * nv2.z) * ilv; vv[11] = (a2.w + beta * nv2.w) * ilv;
        vv[12] = (a3.x + beta * nv3.x) * ilv; vv[13] = (a3.y + beta * nv3.y) * ilv;
        vv[14] = (a3.z + beta * nv3.z) * ilv; vv[15] = (a3.w + beta * nv3.w) * ilv;
#pragma unroll
        for (int g = 0; g < 4; ++g) {
            ushort4 hi4, lo4;
            hi4.x = f2bf(vv[g * 4 + 0]); lo4.x = f2bf(vv[g * 4 + 0] - bf2f(hi4.x));
            hi4.y = f2bf(vv[g * 4 + 1]); lo4.y = f2bf(vv[g * 4 + 1] - bf2f(hi4.y));
            hi4.z = f2bf(vv[g * 4 + 2]); lo4.z = f2bf(vv[g * 4 + 2] - bf2f(hi4.z));
            hi4.w = f2bf(vv[g * 4 + 3]); lo4.w = f2bf(vv[g * 4 + 3] - bf2f(hi4.w));
            *(ushort4*)&ih[ob + g * 4] = hi4;
            *(ushort4*)&il[ob + g * 4] = lo4;
        }
    }
}

// ---------------- Kernel 3: output projection (split-bf16 MFMA, 32-wide j tiles) ----------------
__global__ __launch_bounds__(256) void k_out(const u16* __restrict__ wo_hi,
                                             const u16* __restrict__ wo_lo,
                                             const u16* __restrict__ ih,
                                             const u16* __restrict__ il,
                                             float* __restrict__ out) {
    const int j0 = blockIdx.x * 32;        // 72 j-tiles of 32 -> 576 blocks
    const int c0 = blockIdx.y * 64;
    const int b  = blockIdx.z;
    const int t  = threadIdx.x;
    const int w = t >> 6, lane = t & 63, mcol = lane & 15, quad = lane >> 4;

    const u16* ah = wo_hi + (size_t)(c0 + w * 16 + mcol) * 512 + quad * 8;
    const u16* al = wo_lo + (size_t)(c0 + w * 16 + mcol) * 512 + quad * 8;
    const u16* xh = ih + ((size_t)b * NPOS + j0 + mcol) * 512 + quad * 8;
    const u16* xl = il + ((size_t)b * NPOS + j0 + mcol) * 512 + quad * 8;

    f32x4 c[2];
#pragma unroll
    for (int nf = 0; nf < 2; ++nf) c[nf] = (f32x4){0.f, 0.f, 0.f, 0.f};
#pragma unroll
    for (int kc = 0; kc < 16; ++kc) {
        const bf16x8 A  = *(const bf16x8*)&ah[kc * 32];
        const bf16x8 Al = *(const bf16x8*)&al[kc * 32];
        bf16x8 Bh[2], Bl[2];
#pragma unroll
        for (int nf = 0; nf < 2; ++nf) {
            Bh[nf] = *(const bf16x8*)&xh[(size_t)nf * 16 * 512 + kc * 32];
            Bl[nf] = *(const bf16x8*)&xl[(size_t)nf * 16 * 512 + kc * 32];
        }
#pragma unroll
        for (int nf = 0; nf < 2; ++nf) {
            c[nf] = __builtin_amdgcn_mfma_f32_16x16x32_bf16(A,  Bh[nf], c[nf], 0, 0, 0);
            c[nf] = __builtin_amdgcn_mfma_f32_16x16x32_bf16(A,  Bl[nf], c[nf], 0, 0, 0);
            c[nf] = __builtin_amdgcn_mfma_f32_16x16x32_bf16(Al, Bh[nf], c[nf], 0, 0, 0);
        }
    }
    float* ob = out + ((size_t)b * CC + c0 + w * 16) * NPOS + j0;
#pragma unroll
    for (int nf = 0; nf < 2; ++nf)
#pragma unroll
        for (int r = 0; r < 4; ++r)
            ob[(size_t)(quad * 4 + r) * NPOS + nf * 16 + mcol] = c[nf][r];
}

extern "C" void kernel_launch(void* const* d_in, const int* in_sizes, int n_in,
                              void* d_out, int out_size, void* d_ws, size_t ws_size,
                              hipStream_t stream) {
    const float* fmap    = (const float*)d_in[0];
    const float* gamma   = (const float*)d_in[1];
    const float* w_qk    = (const float*)d_in[2];
    const float* w_v     = (const float*)d_in[3];
    const float* null_kv = (const float*)d_in[4];
    const float* w_out   = (const float*)d_in[5];
    float* out = (float*)d_out;

    u16* ws16 = (u16*)d_ws;
    u16* qkh    = ws16;                     // 16*2304*64  = 2,359,296 u16
    u16* vtb    = qkh + 2359296;            // 16*72*64*32 = 2,359,296
    u16* in_hi  = vtb + 2359296;            // 2*2304*512  = 2,359,296
    u16* in_lo  = in_hi + 2359296;          //               2,359,296
    u16* wo_hi  = in_lo + 2359296;          // 256*512     =   131,072
    u16* wo_lo  = wo_hi + 131072;           //                 131,072
    float* sqbuf = (float*)(wo_lo + 131072);    // 36,864 f32
    float* ndbuf = sqbuf + 36864;               // 36,864
    float* nk2b  = ndbuf + 36864;               // 8
    // total ~ 19.5 MB

    hipLaunchKernelGGL(k_proj, dim3(648),       dim3(256), 0, stream,
                       fmap, gamma, w_qk, w_v, w_out, null_kv, qkh, vtb, sqbuf, ndbuf, nk2b, wo_hi, wo_lo);
    hipLaunchKernelGGL(k_attn, dim3(576),       dim3(256), 0, stream,
                       qkh, vtb, null_kv, nk2b, sqbuf, ndbuf, in_hi, in_lo);
    hipLaunchKernelGGL(k_out,  dim3(72, 4, 2),  dim3(256), 0, stream,
                       wo_hi, wo_lo, in_hi, in_lo, out);
}

// Round 5
// 179.232 us; speedup vs baseline: 1.0890x; 1.0890x over previous
//
#include <hip/hip_runtime.h>
#include <math.h>

#define NPOS 2304   // 48*48
#define CC   256    // DIM
#define DI   512    // HEADS*DIM_HEAD
#define NT   36     // NPOS/64
#define SCALE 0.125f
#define MASKV -100.0f
// exp(-SCALE*sqrt(d2)) = exp2(-SCALE*log2(e)*sqrt(d2))
#define NEGSL2E (-0.18033688011112042f)

typedef __attribute__((ext_vector_type(8))) short bf16x8;  // 8 bf16 (4 VGPRs)
typedef __attribute__((ext_vector_type(4))) float f32x4;   // MFMA C/D frag
typedef unsigned short u16;
typedef unsigned int u32;

__device__ inline u16 f2bf(float f) {
    union { float f; unsigned int u; } v; v.f = f;
    return (u16)((v.u + 0x7fffu + ((v.u >> 16) & 1u)) >> 16);
}
__device__ inline float bf2f(u16 h) { return __uint_as_float(((u32)h) << 16); }

// assemble a bf16x8 frag from 8-byte-aligned LDS via two b64 reads
__device__ inline bf16x8 ld_x8(const u16* p) {
    union { bf16x8 v; uint2 d[2]; } u;
    u.d[0] = *(const uint2*)(p + 0);
    u.d[1] = *(const uint2*)(p + 4);
    return u.v;
}

// async global->LDS DMA, 16B per lane (dest = wave-uniform base + lane*16)
__device__ __forceinline__ void gl16(const u16* g, u16* l) {
    __builtin_amdgcn_global_load_lds(
        (const __attribute__((address_space(1))) void*)g,
        (__attribute__((address_space(3))) void*)l, 16, 0, 0);
}

// ---------------- Kernel 1: fused rmsnorm + paired qk/v MFMA projection ----------------
// XCD-aligned 1D grid: blk<576 -> xcd=blk&7 produces bh=xcd*2+(r&1), matching
// k_attn's consumer swizzle so each (b,h)'s qkh/vt/sq/ndot sit in the local L2.
// blk in [576,648): one-time w_out hi/lo split.
__global__ __launch_bounds__(256) void k_proj(const float* __restrict__ fmap,
                                              const float* __restrict__ gamma,
                                              const float* __restrict__ wqk,
                                              const float* __restrict__ wv,
                                              const float* __restrict__ wout,
                                              const float* __restrict__ null_kv,
                                              u16* __restrict__ qkh,
                                              u16* __restrict__ vt,
                                              float* __restrict__ sq,
                                              float* __restrict__ ndot,
                                              float* __restrict__ nk2b,
                                              u16* __restrict__ wo_hi,
                                              u16* __restrict__ wo_lo) {
    const int blk = blockIdx.x;
    if (blk >= 576) {                     // w_out hi/lo split (no LDS use, early out)
        const int idx = blk - 576;        // 0..71
#pragma unroll
        for (int it = 0; it < 2; ++it) {
            const int k = idx * 512 + (int)threadIdx.x + it * 256;
            if (k < 32768) {
                const float4 v = ((const float4*)wout)[k];
                ushort4 h4, l4;
                h4.x = f2bf(v.x); l4.x = f2bf(v.x - bf2f(h4.x));
                h4.y = f2bf(v.y); l4.y = f2bf(v.y - bf2f(h4.y));
                h4.z = f2bf(v.z); l4.z = f2bf(v.z - bf2f(h4.z));
                h4.w = f2bf(v.w); l4.w = f2bf(v.w - bf2f(h4.w));
                ((ushort4*)wo_hi)[k] = h4;
                ((ushort4*)wo_lo)[k] = l4;
            }
        }
        return;
    }
    // XCD-aligned decode: bh pair per XCD matches k_attn (bh = xcd*2 + parity)
    const int xcd = blk & 7;
    const int r   = blk >> 3;             // 0..71
    const int bh  = xcd * 2 + (r & 1);    // 0..15
    const int b   = bh >> 3;
    const int oy  = bh & 7;               // head
    const int n0  = (r >> 1) * 64;        // 36 position tiles

    const int t  = threadIdx.x;
    const int w = t >> 6, lane = t & 63, mcol = lane & 15, quad = lane >> 4;
    const int tx = t & 63, ty = t >> 6;

    __shared__ u16 X[64][260];            // [pos][chan]; dword pitch 130, rows 8B-aligned
    __shared__ float red[4][64];
    __shared__ float inv_s[64];
    __shared__ float gs[256];
    __shared__ float sqp[4][64], ndp[4][64];
    u16 (*Tt)[68] = (u16(*)[68])X;        // aliased after phase B

    // ---- phase A: rmsnorm, fmap held in registers (single global pass) ----
    gs[t] = gamma[t];
    const float* fb = fmap + (size_t)b * CC * NPOS;
    float v64[64];
#pragma unroll
    for (int i = 0; i < 64; ++i)
        v64[i] = fb[(ty * 64 + i) * NPOS + n0 + tx];
    float s = 0.0f;
#pragma unroll
    for (int i = 0; i < 64; ++i) s += v64[i] * v64[i];
    red[ty][tx] = s;
    __syncthreads();
    if (t < 64) {
        const float tt = red[0][t] + red[1][t] + red[2][t] + red[3][t];
        inv_s[t] = 16.0f / fmaxf(sqrtf(tt), 1e-12f);
    }
    __syncthreads();
    const float iv = inv_s[tx];
#pragma unroll
    for (int i = 0; i < 64; i += 2) {
        const int c = ty * 64 + i;
        const float v0 = v64[i] * iv * gs[c];
        const float v1 = v64[i + 1] * iv * gs[c + 1];
        *(u32*)&X[tx][c] = (u32)f2bf(v0) | ((u32)f2bf(v1) << 16);   // bank 2-way: free
    }
    if (blk == 0 && t < 8) {
        float s2 = 0.0f;
#pragma unroll 8
        for (int d = 0; d < 64; ++d) { const float x = null_kv[t * 64 + d]; s2 += x * x; }
        nk2b[t] = s2;
    }
    __syncthreads();

    // ---- phase B (dual): one X frag read feeds qk-head AND v-head MFMA ----
    const size_t wroff = (size_t)(oy * 64 + w * 16 + mcol) * 256 + quad * 8;
    const float* wrq = wqk + wroff;
    const float* wrv = wv + wroff;

    f32x4 cq[4], cv[4];
#pragma unroll
    for (int nf = 0; nf < 4; ++nf) {
        cq[nf] = (f32x4){0.f, 0.f, 0.f, 0.f};
        cv[nf] = (f32x4){0.f, 0.f, 0.f, 0.f};
    }
#pragma unroll
    for (int kc = 0; kc < 8; ++kc) {
        const float4 qa = *(const float4*)&wrq[kc * 32];
        const float4 qb4 = *(const float4*)&wrq[kc * 32 + 4];
        const float4 va = *(const float4*)&wrv[kc * 32];
        const float4 vb4 = *(const float4*)&wrv[kc * 32 + 4];
        bf16x8 aq, av;
        aq[0] = f2bf(qa.x);  aq[1] = f2bf(qa.y);  aq[2] = f2bf(qa.z);  aq[3] = f2bf(qa.w);
        aq[4] = f2bf(qb4.x); aq[5] = f2bf(qb4.y); aq[6] = f2bf(qb4.z); aq[7] = f2bf(qb4.w);
        av[0] = f2bf(va.x);  av[1] = f2bf(va.y);  av[2] = f2bf(va.z);  av[3] = f2bf(va.w);
        av[4] = f2bf(vb4.x); av[5] = f2bf(vb4.y); av[6] = f2bf(vb4.z); av[7] = f2bf(vb4.w);
        bf16x8 xB[4];
#pragma unroll
        for (int nf = 0; nf < 4; ++nf)
            xB[nf] = ld_x8(&X[nf * 16 + mcol][kc * 32 + quad * 8]);
#pragma unroll
        for (int nf = 0; nf < 4; ++nf) {
            cq[nf] = __builtin_amdgcn_mfma_f32_16x16x32_bf16(aq, xB[nf], cq[nf], 0, 0, 0);
            cv[nf] = __builtin_amdgcn_mfma_f32_16x16x32_bf16(av, xB[nf], cv[nf], 0, 0, 0);
        }
    }
    __syncthreads();   // all X reads done; Tt alias safe

    // ---- epilogue 1: qk head -> qkh + sq/ndot ----
    {
        const int h = oy;   // d = w*16 + quad*4 + r, n = n0 + nf*16 + mcol
        const float4 nk4 = *(const float4*)&null_kv[h * 64 + w * 16 + quad * 4];
        float sv[4], nd[4];
#pragma unroll
        for (int nf = 0; nf < 4; ++nf) {
            sv[nf] = cq[nf][0] * cq[nf][0] + cq[nf][1] * cq[nf][1] + cq[nf][2] * cq[nf][2] + cq[nf][3] * cq[nf][3];
            nd[nf] = cq[nf][0] * nk4.x + cq[nf][1] * nk4.y + cq[nf][2] * nk4.z + cq[nf][3] * nk4.w;
        }
#pragma unroll
        for (int mk = 16; mk <= 32; mk <<= 1)
#pragma unroll
            for (int nf = 0; nf < 4; ++nf) {
                sv[nf] += __shfl_xor(sv[nf], mk);
                nd[nf] += __shfl_xor(nd[nf], mk);
            }
        if (quad == 0) {
#pragma unroll
            for (int nf = 0; nf < 4; ++nf) {
                sqp[w][nf * 16 + mcol] = sv[nf];
                ndp[w][nf * 16 + mcol] = nd[nf];
            }
        }
#pragma unroll
        for (int nf = 0; nf < 4; ++nf) {
            ushort4 r4;
            r4.x = f2bf(cq[nf][0]); r4.y = f2bf(cq[nf][1]);
            r4.z = f2bf(cq[nf][2]); r4.w = f2bf(cq[nf][3]);
            *(ushort4*)&Tt[nf * 16 + mcol][w * 16 + quad * 4] = r4;   // Tt[n][d]
        }
        __syncthreads();
        {
            const int n = t >> 2, ds = (t & 3) * 16;
            const uint2 r0 = *(const uint2*)&Tt[n][ds + 0];
            const uint2 r1 = *(const uint2*)&Tt[n][ds + 4];
            const uint2 r2 = *(const uint2*)&Tt[n][ds + 8];
            const uint2 r3 = *(const uint2*)&Tt[n][ds + 12];
            u16* dst = qkh + (((size_t)bh) * NPOS + n0 + n) * 64 + ds;
            *(uint4*)&dst[0] = make_uint4(r0.x, r0.y, r1.x, r1.y);
            *(uint4*)&dst[8] = make_uint4(r2.x, r2.y, r3.x, r3.y);
        }
        if (t < 64) {
            sq  [((size_t)bh) * NPOS + n0 + t] = sqp[0][t] + sqp[1][t] + sqp[2][t] + sqp[3][t];
            ndot[((size_t)bh) * NPOS + n0 + t] = ndp[0][t] + ndp[1][t] + ndp[2][t] + ndp[3][t];
        }
    }
    __syncthreads();   // qk readback done before Tt reuse

    // ---- epilogue 2: v head -> vt frag-ordered ----
    {
#pragma unroll
        for (int nf = 0; nf < 4; ++nf)
#pragma unroll
            for (int rr = 0; rr < 4; ++rr)
                Tt[w * 16 + quad * 4 + rr][nf * 16 + mcol] = f2bf(cv[nf][rr]);  // Tt[d][key]
        __syncthreads();
        {
            const int d = t >> 2, ks = t & 3;
            const uint2 a0 = *(const uint2*)&Tt[d][ks * 16 + 0];
            const uint2 a1 = *(const uint2*)&Tt[d][ks * 16 + 4];
            const uint2 a2 = *(const uint2*)&Tt[d][ks * 16 + 8];
            const uint2 a3 = *(const uint2*)&Tt[d][ks * 16 + 12];
            u16* vdst = vt + (size_t)bh * (72 * 64 * 32);
            const int kb = (n0 >> 5) + (ks >> 1);
            u16* p = &vdst[((size_t)kb * 64 + d) * 32 + (ks & 1) * 16];
            *(uint4*)&p[0] = make_uint4(a0.x, a0.y, a1.x, a1.y);
            *(uint4*)&p[8] = make_uint4(a2.x, a2.y, a3.x, a3.y);
        }
    }
}

// ---------------- Kernel 2: LDS-staged flash attention, 64 q/block, async DMA staging ----------------
// R17 = R4 with the staging path replaced by __builtin_amdgcn_global_load_lds
// (width 16) + XOR-swizzled LINEAR LDS layouts (rule #21: gload_lds writes
// linearly -> swizzle applied to the per-lane GLOBAL source address AND the
// LDS read address, same involution; LDS dest stays linear).
//   K: [64][64] u16 (128B rows), involution g ^= (row&7)   -> conflict-free b128 reads
//   V: [2][64][32] u16 (64B rows), involution g ^= ((row>>1)&3) -> 2-way max (free)
// Removes per tile: 8 uint4 reg loads + 8 ds_writes + the ds_write->barrier->
// ds_read turnaround (~300-400cy serial per tile, in lockstep for all waves).
// DMA for tile t+1 issued at top of tile t; the compiler's vmcnt(0) before
// s_barrier drains it at the t+1 barrier after a full tile of compute.
// k2 loads issued BEFORE the DMAs so their vmcnt wait doesn't drain the DMA queue.
// Compute core / Pt / epilogue identical to R4 (bit-identical arithmetic).
__global__ __launch_bounds__(256) void k_attn(const u16* __restrict__ qkh,
                                              const u16* __restrict__ vt,
                                              const float* __restrict__ null_kv,
                                              const float* __restrict__ nk2b,
                                              const float* __restrict__ sq,
                                              const float* __restrict__ ndot,
                                              u16* __restrict__ ih,
                                              u16* __restrict__ il) {
    const int blk = blockIdx.x;             // 576
    const int xcd = blk & 7;
    const int j = blk >> 3;                 // 0..71
    const int bh = xcd * 2 + (j & 1);       // XCD-local bh pair
    const int qt = j >> 1;                  // 0..35
    const int q0 = qt * 64;
    const int b = bh >> 3, h = bh & 7;
    const int t = threadIdx.x;
    const int wave = t >> 6, lane = t & 63;
    const int mcol = lane & 15, quad = lane >> 4;

    // sm layout (u16 units): [0,8192)=K 2 bufs x [64][64]; [8192,16384)=V 2 bufs
    // x [2 sub][64][32]; [16384,20992)=Pt 4 waves x [16][72]. Epilogue aliases
    // the K/V region as f32 scratch.
    __shared__ __align__(16) u16 sm[20992];
    u16* Kls = sm;
    u16* Vls = sm + 8192;
    u16 (*Pt)[72] = (u16(*)[72])(sm + 16384 + wave * 1152);

    const u16* qbase = qkh + (size_t)bh * NPOS * 64;
    const u16* vbase = vt + (size_t)bh * (72 * 64 * 32);
    const float* sqb = sq + (size_t)bh * NPOS;

    const int q16 = q0 + wave * 16;
    const bf16x8 bq00 = *(const bf16x8*)&qbase[(q16 + mcol) * 64 + quad * 8];
    const bf16x8 bq01 = *(const bf16x8*)&qbase[(q16 + mcol) * 64 + 32 + quad * 8];
    const float q2 = sqb[q16 + mcol];
    const int ktm = q16 >> 6;               // k-tile containing the self-masked key
    const int nbm = (q16 >> 4) & 3;

    // ---- staging offsets (u16 units) ----
    // K: wave w covers rows [w*16, w*16+16) as 2 chunks of 8 rows (1KB each).
    //    lane l -> row base+ (l>>3), granule (l&7); source granule ^= (l>>3).
    const int kbase0 = (wave * 16 + 0) * 64;            // LDS chunk base (uniform)
    const int kbase1 = (wave * 16 + 8) * 64;
    const int ksrc0 = (wave * 16 + 0 + (lane >> 3)) * 64 + ((lane & 7) ^ (lane >> 3)) * 8;
    const int ksrc1 = (wave * 16 + 8 + (lane >> 3)) * 64 + ((lane & 7) ^ (lane >> 3)) * 8;
    // V: per sub s, wave w covers rows [w*16, w*16+16) (1KB). lane l -> row
    //    base+(l>>2), granule (l&3); source granule ^= ((l>>3)&3).
    const int vldsb = wave * 512;                       // within a sub (uniform)
    const int vsrc = (wave * 16 + (lane >> 2)) * 32 + ((lane & 3) ^ ((lane >> 3) & 3)) * 8;

    // read-side swizzles
    const int m7 = mcol & 7;
    const int mv = (mcol >> 1) & 3;

    {   // prologue: stage tile 0 into buf 0
        gl16(qbase + ksrc0, Kls + kbase0);
        gl16(qbase + ksrc1, Kls + kbase1);
        gl16(vbase + vsrc,        Vls + vldsb);
        gl16(vbase + 2048 + vsrc, Vls + 2048 + vldsb);
    }

    const bf16x8 ones = {0x3F80, 0x3F80, 0x3F80, 0x3F80, 0x3F80, 0x3F80, 0x3F80, 0x3F80};

    f32x4 oacc[4];
#pragma unroll
    for (int nb = 0; nb < 4; ++nb) oacc[nb] = (f32x4){0.f, 0.f, 0.f, 0.f};
    f32x4 lsum = (f32x4){0.f, 0.f, 0.f, 0.f};

    int p = 0;
#pragma unroll 1
    for (int kt = 0; kt < 36; ++kt) {
        __syncthreads();                    // vmcnt(0) drain -> buf[p] DMA complete
        // k2 loads FIRST (oldest vmcnt slots -> consumed without draining DMAs)
        float4 k2q[4];
#pragma unroll
        for (int nb = 0; nb < 4; ++nb)
            k2q[nb] = *(const float4*)&sqb[kt * 64 + nb * 16 + quad * 4];
        // issue next tile's DMA into buf p^1 (readers finished before barrier)
        if (kt + 1 < 36) {
            const u16* kg = qbase + (size_t)(kt + 1) * 4096;
            const u16* vg = vbase + (size_t)(kt + 1) * 4096;
            const int bb = (p ^ 1) * 4096;
            gl16(kg + ksrc0, Kls + bb + kbase0);
            gl16(kg + ksrc1, Kls + bb + kbase1);
            gl16(vg + vsrc,        Vls + bb + vldsb);
            gl16(vg + 2048 + vsrc, Vls + bb + 2048 + vldsb);
        }

        const u16* Kb = Kls + p * 4096;
        const u16* Vb = Vls + p * 4096;

        bf16x8 bk[4][2];
#pragma unroll
        for (int nb = 0; nb < 4; ++nb) {
            const int rr = (nb * 16 + mcol) * 64;
            bk[nb][0] = *(const bf16x8*)&Kb[rr + ((quad ^ m7)) * 8];
            bk[nb][1] = *(const bf16x8*)&Kb[rr + (((4 + quad) ^ m7)) * 8];
        }

        f32x4 c[4];
#pragma unroll
        for (int nb = 0; nb < 4; ++nb) {
            c[nb] = (f32x4){0.f, 0.f, 0.f, 0.f};
            c[nb] = __builtin_amdgcn_mfma_f32_16x16x32_bf16(bk[nb][0], bq00, c[nb], 0, 0, 0);
            c[nb] = __builtin_amdgcn_mfma_f32_16x16x32_bf16(bk[nb][1], bq01, c[nb], 0, 0, 0);
        }

        bf16x8 bv[4][2];
#pragma unroll
        for (int nb = 0; nb < 4; ++nb) {
            const int rr = (nb * 16 + mcol) * 32 + ((quad ^ mv)) * 8;
            bv[nb][0] = *(const bf16x8*)&Vb[rr];
            bv[nb][1] = *(const bf16x8*)&Vb[2048 + rr];
        }

#pragma unroll
        for (int nb = 0; nb < 4; ++nb) {
            float e[4];
#pragma unroll
            for (int r = 0; r < 4; ++r) {
                const float pre = q2 + ((const float*)&k2q[nb])[r];
                const float d2 = fmaxf(__builtin_fmaf(c[nb][r], -2.0f, pre), 0.0f);
                e[r] = __builtin_amdgcn_exp2f(NEGSL2E * __builtin_amdgcn_sqrtf(d2));
            }
            if (kt == ktm && nb == nbm) {
#pragma unroll
                for (int r = 0; r < 4; ++r)
                    if (quad * 4 + r == mcol) e[r] = 0.0f;   // exp(MASKV) ~ 0
            }
            const u32 p01 = __builtin_amdgcn_perm(__float_as_uint(e[1]), __float_as_uint(e[0]), 0x07060302u);
            const u32 p23 = __builtin_amdgcn_perm(__float_as_uint(e[3]), __float_as_uint(e[2]), 0x07060302u);
            *(uint2*)&Pt[mcol][nb * 16 + quad * 4] = make_uint2(p01, p23);
        }

        const bf16x8 bp00 = *(const bf16x8*)&Pt[mcol][quad * 8];
        const bf16x8 bp01 = *(const bf16x8*)&Pt[mcol][32 + quad * 8];

#pragma unroll
        for (int nb = 0; nb < 4; ++nb) {
            oacc[nb] = __builtin_amdgcn_mfma_f32_16x16x32_bf16(bv[nb][0], bp00, oacc[nb], 0, 0, 0);
            oacc[nb] = __builtin_amdgcn_mfma_f32_16x16x32_bf16(bv[nb][1], bp01, oacc[nb], 0, 0, 0);
        }
        lsum = __builtin_amdgcn_mfma_f32_16x16x32_bf16(ones, bp00, lsum, 0, 0, 0);
        lsum = __builtin_amdgcn_mfma_f32_16x16x32_bf16(ones, bp01, lsum, 0, 0, 0);

        p ^= 1;
    }

    __syncthreads();                        // main loop done; K/V region reusable

    // ---- per-wave finalize: transpose via LDS (alias K/V region), no cross-wave merge ----
    float* Ofin = (float*)sm + wave * (16 * 68);   // 4 waves x 16 q x 68 f32 = 17.4KB < 32KB
#pragma unroll
    for (int nb = 0; nb < 4; ++nb)
        *(f32x4*)&Ofin[mcol * 68 + nb * 16 + quad * 4] = oacc[nb];
    if (quad == 0) Ofin[mcol * 68 + 64] = lsum[0];

    {
        const int q = lane >> 2;            // 0..15
        const int d0 = (lane & 3) * 16;     // 0, 16, 32, 48
        const float4 a0 = *(const float4*)&Ofin[q * 68 + d0 + 0];
        const float4 a1 = *(const float4*)&Ofin[q * 68 + d0 + 4];
        const float4 a2 = *(const float4*)&Ofin[q * 68 + d0 + 8];
        const float4 a3 = *(const float4*)&Ofin[q * 68 + d0 + 12];
        const float l = Ofin[q * 68 + 64];

        const int qg = q16 + q;
        const float q2v = sqb[qg];
        const float nd = ndot[(size_t)bh * NPOS + qg];
        const float nk2 = nk2b[h];
        const float d2n = fmaxf(q2v + nk2 - 2.0f * nd, 0.0f);
        const float beta = __expf(-sqrtf(d2n) * SCALE);
        const float ilv = 1.0f / (l + beta);

        const float* nvp = &null_kv[DI + h * 64 + d0];
        const float4 nv0 = *(const float4*)&nvp[0];
        const float4 nv1 = *(const float4*)&nvp[4];
        const float4 nv2 = *(const float4*)&nvp[8];
        const float4 nv3 = *(const float4*)&nvp[12];

        const size_t ob = ((size_t)b * NPOS + qg) * DI + h * 64 + d0;
        float vv[16];
        vv[0]  = (a0.x + beta * nv0.x) * ilv; vv[1]  = (a0.y + beta * nv0.y) * ilv;
        vv[2]  = (a0.z + beta * nv0.z) * ilv; vv[3]  = (a0.w + beta * nv0.w) * ilv;
        vv[4]  = (a1.x + beta * nv1.x) * ilv; vv[5]  = (a1.y + beta * nv1.y) * ilv;
        vv[6]  = (a1.z + beta * nv1.z) * ilv; vv[7]  = (a1.w + beta * nv1.w) * ilv;
        vv[8]  = (a2.x + beta * nv2.x) * ilv; vv[9]  = (a2.y + beta * nv2.y) * ilv;
        vv[10] = (a2.z + beta * nv2.z) * ilv; vv[11] = (a2.w + beta * nv2.w) * ilv;
        vv[12] = (a3.x + beta * nv3.x) * ilv; vv[13] = (a3.y + beta * nv3.y) * ilv;
        vv[14] = (a3.z + beta * nv3.z) * ilv; vv[15] = (a3.w + beta * nv3.w) * ilv;
#pragma unroll
        for (int g = 0; g < 4; ++g) {
            ushort4 hi4, lo4;
            hi4.x = f2bf(vv[g * 4 + 0]); lo4.x = f2bf(vv[g * 4 + 0] - bf2f(hi4.x));
            hi4.y = f2bf(vv[g * 4 + 1]); lo4.y = f2bf(vv[g * 4 + 1] - bf2f(hi4.y));
            hi4.z = f2bf(vv[g * 4 + 2]); lo4.z = f2bf(vv[g * 4 + 2] - bf2f(hi4.z));
            hi4.w = f2bf(vv[g * 4 + 3]); lo4.w = f2bf(vv[g * 4 + 3] - bf2f(hi4.w));
            *(ushort4*)&ih[ob + g * 4] = hi4;
            *(ushort4*)&il[ob + g * 4] = lo4;
        }
    }
}

// ---------------- Kernel 3: output projection (split-bf16 MFMA, 32-wide j tiles) ----------------
__global__ __launch_bounds__(256) void k_out(const u16* __restrict__ wo_hi,
                                             const u16* __restrict__ wo_lo,
                                             const u16* __restrict__ ih,
                                             const u16* __restrict__ il,
                                             float* __restrict__ out) {
    const int j0 = blockIdx.x * 32;        // 72 j-tiles of 32 -> 576 blocks
    const int c0 = blockIdx.y * 64;
    const int b  = blockIdx.z;
    const int t  = threadIdx.x;
    const int w = t >> 6, lane = t & 63, mcol = lane & 15, quad = lane >> 4;

    const u16* ah = wo_hi + (size_t)(c0 + w * 16 + mcol) * 512 + quad * 8;
    const u16* al = wo_lo + (size_t)(c0 + w * 16 + mcol) * 512 + quad * 8;
    const u16* xh = ih + ((size_t)b * NPOS + j0 + mcol) * 512 + quad * 8;
    const u16* xl = il + ((size_t)b * NPOS + j0 + mcol) * 512 + quad * 8;

    f32x4 c[2];
#pragma unroll
    for (int nf = 0; nf < 2; ++nf) c[nf] = (f32x4){0.f, 0.f, 0.f, 0.f};
#pragma unroll
    for (int kc = 0; kc < 16; ++kc) {
        const bf16x8 A  = *(const bf16x8*)&ah[kc * 32];
        const bf16x8 Al = *(const bf16x8*)&al[kc * 32];
        bf16x8 Bh[2], Bl[2];
#pragma unroll
        for (int nf = 0; nf < 2; ++nf) {
            Bh[nf] = *(const bf16x8*)&xh[(size_t)nf * 16 * 512 + kc * 32];
            Bl[nf] = *(const bf16x8*)&xl[(size_t)nf * 16 * 512 + kc * 32];
        }
#pragma unroll
        for (int nf = 0; nf < 2; ++nf) {
            c[nf] = __builtin_amdgcn_mfma_f32_16x16x32_bf16(A,  Bh[nf], c[nf], 0, 0, 0);
            c[nf] = __builtin_amdgcn_mfma_f32_16x16x32_bf16(A,  Bl[nf], c[nf], 0, 0, 0);
            c[nf] = __builtin_amdgcn_mfma_f32_16x16x32_bf16(Al, Bh[nf], c[nf], 0, 0, 0);
        }
    }
    float* ob = out + ((size_t)b * CC + c0 + w * 16) * NPOS + j0;
#pragma unroll
    for (int nf = 0; nf < 2; ++nf)
#pragma unroll
        for (int r = 0; r < 4; ++r)
            ob[(size_t)(quad * 4 + r) * NPOS + nf * 16 + mcol] = c[nf][r];
}

extern "C" void kernel_launch(void* const* d_in, const int* in_sizes, int n_in,
                              void* d_out, int out_size, void* d_ws, size_t ws_size,
                              hipStream_t stream) {
    const float* fmap    = (const float*)d_in[0];
    const float* gamma   = (const float*)d_in[1];
    const float* w_qk    = (const float*)d_in[2];
    const float* w_v     = (const float*)d_in[3];
    const float* null_kv = (const float*)d_in[4];
    const float* w_out   = (const float*)d_in[5];
    float* out = (float*)d_out;

    u16* ws16 = (u16*)d_ws;
    u16* qkh    = ws16;                     // 16*2304*64  = 2,359,296 u16
    u16* vtb    = qkh + 2359296;            // 16*72*64*32 = 2,359,296
    u16* in_hi  = vtb + 2359296;            // 2*2304*512  = 2,359,296
    u16* in_lo  = in_hi + 2359296;          //               2,359,296
    u16* wo_hi  = in_lo + 2359296;          // 256*512     =   131,072
    u16* wo_lo  = wo_hi + 131072;           //                 131,072
    float* sqbuf = (float*)(wo_lo + 131072);    // 36,864 f32
    float* ndbuf = sqbuf + 36864;               // 36,864
    float* nk2b  = ndbuf + 36864;               // 8
    // total ~ 19.5 MB

    hipLaunchKernelGGL(k_proj, dim3(648),       dim3(256), 0, stream,
                       fmap, gamma, w_qk, w_v, w_out, null_kv, qkh, vtb, sqbuf, ndbuf, nk2b, wo_hi, wo_lo);
    hipLaunchKernelGGL(k_attn, dim3(576),       dim3(256), 0, stream,
                       qkh, vtb, null_kv, nk2b, sqbuf, ndbuf, in_hi, in_lo);
    hipLaunchKernelGGL(k_out,  dim3(72, 4, 2),  dim3(256), 0, stream,
                       wo_hi, wo_lo, in_hi, in_lo, out);
}

// Round 6
// 178.595 us; speedup vs baseline: 1.0929x; 1.0036x over previous
//
#include <hip/hip_runtime.h>
#include <math.h>

#define NPOS 2304   // 48*48
#define CC   256    // DIM
#define DI   512    // HEADS*DIM_HEAD
#define NT   36     // NPOS/64
#define SCALE 0.125f
#define MASKV -100.0f
// exp(-SCALE*sqrt(d2)) = exp2(-SCALE*log2(e)*sqrt(d2))
#define NEGSL2E (-0.18033688011112042f)

typedef __attribute__((ext_vector_type(8))) short bf16x8;  // 8 bf16 (4 VGPRs)
typedef __attribute__((ext_vector_type(4))) float f32x4;   // MFMA C/D frag
typedef unsigned short u16;
typedef unsigned int u32;

__device__ inline u16 f2bf(float f) {
    union { float f; unsigned int u; } v; v.f = f;
    return (u16)((v.u + 0x7fffu + ((v.u >> 16) & 1u)) >> 16);
}
__device__ inline float bf2f(u16 h) { return __uint_as_float(((u32)h) << 16); }

// assemble a bf16x8 frag from 8-byte-aligned LDS via two b64 reads
__device__ inline bf16x8 ld_x8(const u16* p) {
    union { bf16x8 v; uint2 d[2]; } u;
    u.d[0] = *(const uint2*)(p + 0);
    u.d[1] = *(const uint2*)(p + 4);
    return u.v;
}

// async global->LDS DMA, 16B per lane (dest = wave-uniform base + lane*16)
__device__ __forceinline__ void gl16(const u16* g, u16* l) {
    __builtin_amdgcn_global_load_lds(
        (const __attribute__((address_space(1))) void*)g,
        (__attribute__((address_space(3))) void*)l, 16, 0, 0);
}

// ---------------- Kernel 1: fused rmsnorm + paired qk/v MFMA projection ----------------
// XCD-aligned 1D grid: blk<576 -> xcd=blk&7 produces bh=xcd*2+(r&1), matching
// k_attn's consumer swizzle so each (b,h)'s qkh/vt/sq/ndot sit in the local L2.
// blk in [576,648): one-time w_out hi/lo split.
__global__ __launch_bounds__(256) void k_proj(const float* __restrict__ fmap,
                                              const float* __restrict__ gamma,
                                              const float* __restrict__ wqk,
                                              const float* __restrict__ wv,
                                              const float* __restrict__ wout,
                                              const float* __restrict__ null_kv,
                                              u16* __restrict__ qkh,
                                              u16* __restrict__ vt,
                                              float* __restrict__ sq,
                                              float* __restrict__ ndot,
                                              float* __restrict__ nk2b,
                                              u16* __restrict__ wo_hi,
                                              u16* __restrict__ wo_lo) {
    const int blk = blockIdx.x;
    if (blk >= 576) {                     // w_out hi/lo split (no LDS use, early out)
        const int idx = blk - 576;        // 0..71
#pragma unroll
        for (int it = 0; it < 2; ++it) {
            const int k = idx * 512 + (int)threadIdx.x + it * 256;
            if (k < 32768) {
                const float4 v = ((const float4*)wout)[k];
                ushort4 h4, l4;
                h4.x = f2bf(v.x); l4.x = f2bf(v.x - bf2f(h4.x));
                h4.y = f2bf(v.y); l4.y = f2bf(v.y - bf2f(h4.y));
                h4.z = f2bf(v.z); l4.z = f2bf(v.z - bf2f(h4.z));
                h4.w = f2bf(v.w); l4.w = f2bf(v.w - bf2f(h4.w));
                ((ushort4*)wo_hi)[k] = h4;
                ((ushort4*)wo_lo)[k] = l4;
            }
        }
        return;
    }
    // XCD-aligned decode: bh pair per XCD matches k_attn (bh = xcd*2 + parity)
    const int xcd = blk & 7;
    const int r   = blk >> 3;             // 0..71
    const int bh  = xcd * 2 + (r & 1);    // 0..15
    const int b   = bh >> 3;
    const int oy  = bh & 7;               // head
    const int n0  = (r >> 1) * 64;        // 36 position tiles

    const int t  = threadIdx.x;
    const int w = t >> 6, lane = t & 63, mcol = lane & 15, quad = lane >> 4;
    const int tx = t & 63, ty = t >> 6;

    __shared__ u16 X[64][260];            // [pos][chan]; dword pitch 130, rows 8B-aligned
    __shared__ float red[4][64];
    __shared__ float inv_s[64];
    __shared__ float gs[256];
    __shared__ float sqp[4][64], ndp[4][64];
    u16 (*Tt)[68] = (u16(*)[68])X;        // aliased after phase B

    // ---- phase A: rmsnorm, fmap held in registers (single global pass) ----
    gs[t] = gamma[t];
    const float* fb = fmap + (size_t)b * CC * NPOS;
    float v64[64];
#pragma unroll
    for (int i = 0; i < 64; ++i)
        v64[i] = fb[(ty * 64 + i) * NPOS + n0 + tx];
    float s = 0.0f;
#pragma unroll
    for (int i = 0; i < 64; ++i) s += v64[i] * v64[i];
    red[ty][tx] = s;
    __syncthreads();
    if (t < 64) {
        const float tt = red[0][t] + red[1][t] + red[2][t] + red[3][t];
        inv_s[t] = 16.0f / fmaxf(sqrtf(tt), 1e-12f);
    }
    __syncthreads();
    const float iv = inv_s[tx];
#pragma unroll
    for (int i = 0; i < 64; i += 2) {
        const int c = ty * 64 + i;
        const float v0 = v64[i] * iv * gs[c];
        const float v1 = v64[i + 1] * iv * gs[c + 1];
        *(u32*)&X[tx][c] = (u32)f2bf(v0) | ((u32)f2bf(v1) << 16);   // bank 2-way: free
    }
    if (blk == 0 && t < 8) {
        float s2 = 0.0f;
#pragma unroll 8
        for (int d = 0; d < 64; ++d) { const float x = null_kv[t * 64 + d]; s2 += x * x; }
        nk2b[t] = s2;
    }
    __syncthreads();

    // ---- phase B (dual): one X frag read feeds qk-head AND v-head MFMA ----
    const size_t wroff = (size_t)(oy * 64 + w * 16 + mcol) * 256 + quad * 8;
    const float* wrq = wqk + wroff;
    const float* wrv = wv + wroff;

    f32x4 cq[4], cv[4];
#pragma unroll
    for (int nf = 0; nf < 4; ++nf) {
        cq[nf] = (f32x4){0.f, 0.f, 0.f, 0.f};
        cv[nf] = (f32x4){0.f, 0.f, 0.f, 0.f};
    }
#pragma unroll
    for (int kc = 0; kc < 8; ++kc) {
        const float4 qa = *(const float4*)&wrq[kc * 32];
        const float4 qb4 = *(const float4*)&wrq[kc * 32 + 4];
        const float4 va = *(const float4*)&wrv[kc * 32];
        const float4 vb4 = *(const float4*)&wrv[kc * 32 + 4];
        bf16x8 aq, av;
        aq[0] = f2bf(qa.x);  aq[1] = f2bf(qa.y);  aq[2] = f2bf(qa.z);  aq[3] = f2bf(qa.w);
        aq[4] = f2bf(qb4.x); aq[5] = f2bf(qb4.y); aq[6] = f2bf(qb4.z); aq[7] = f2bf(qb4.w);
        av[0] = f2bf(va.x);  av[1] = f2bf(va.y);  av[2] = f2bf(va.z);  av[3] = f2bf(va.w);
        av[4] = f2bf(vb4.x); av[5] = f2bf(vb4.y); av[6] = f2bf(vb4.z); av[7] = f2bf(vb4.w);
        bf16x8 xB[4];
#pragma unroll
        for (int nf = 0; nf < 4; ++nf)
            xB[nf] = ld_x8(&X[nf * 16 + mcol][kc * 32 + quad * 8]);
#pragma unroll
        for (int nf = 0; nf < 4; ++nf) {
            cq[nf] = __builtin_amdgcn_mfma_f32_16x16x32_bf16(aq, xB[nf], cq[nf], 0, 0, 0);
            cv[nf] = __builtin_amdgcn_mfma_f32_16x16x32_bf16(av, xB[nf], cv[nf], 0, 0, 0);
        }
    }
    __syncthreads();   // all X reads done; Tt alias safe

    // ---- epilogue 1: qk head -> qkh + sq/ndot ----
    {
        const int h = oy;   // d = w*16 + quad*4 + r, n = n0 + nf*16 + mcol
        const float4 nk4 = *(const float4*)&null_kv[h * 64 + w * 16 + quad * 4];
        float sv[4], nd[4];
#pragma unroll
        for (int nf = 0; nf < 4; ++nf) {
            sv[nf] = cq[nf][0] * cq[nf][0] + cq[nf][1] * cq[nf][1] + cq[nf][2] * cq[nf][2] + cq[nf][3] * cq[nf][3];
            nd[nf] = cq[nf][0] * nk4.x + cq[nf][1] * nk4.y + cq[nf][2] * nk4.z + cq[nf][3] * nk4.w;
        }
#pragma unroll
        for (int mk = 16; mk <= 32; mk <<= 1)
#pragma unroll
            for (int nf = 0; nf < 4; ++nf) {
                sv[nf] += __shfl_xor(sv[nf], mk);
                nd[nf] += __shfl_xor(nd[nf], mk);
            }
        if (quad == 0) {
#pragma unroll
            for (int nf = 0; nf < 4; ++nf) {
                sqp[w][nf * 16 + mcol] = sv[nf];
                ndp[w][nf * 16 + mcol] = nd[nf];
            }
        }
#pragma unroll
        for (int nf = 0; nf < 4; ++nf) {
            ushort4 r4;
            r4.x = f2bf(cq[nf][0]); r4.y = f2bf(cq[nf][1]);
            r4.z = f2bf(cq[nf][2]); r4.w = f2bf(cq[nf][3]);
            *(ushort4*)&Tt[nf * 16 + mcol][w * 16 + quad * 4] = r4;   // Tt[n][d]
        }
        __syncthreads();
        {
            const int n = t >> 2, ds = (t & 3) * 16;
            const uint2 r0 = *(const uint2*)&Tt[n][ds + 0];
            const uint2 r1 = *(const uint2*)&Tt[n][ds + 4];
            const uint2 r2 = *(const uint2*)&Tt[n][ds + 8];
            const uint2 r3 = *(const uint2*)&Tt[n][ds + 12];
            u16* dst = qkh + (((size_t)bh) * NPOS + n0 + n) * 64 + ds;
            *(uint4*)&dst[0] = make_uint4(r0.x, r0.y, r1.x, r1.y);
            *(uint4*)&dst[8] = make_uint4(r2.x, r2.y, r3.x, r3.y);
        }
        if (t < 64) {
            sq  [((size_t)bh) * NPOS + n0 + t] = sqp[0][t] + sqp[1][t] + sqp[2][t] + sqp[3][t];
            ndot[((size_t)bh) * NPOS + n0 + t] = ndp[0][t] + ndp[1][t] + ndp[2][t] + ndp[3][t];
        }
    }
    __syncthreads();   // qk readback done before Tt reuse

    // ---- epilogue 2: v head -> vt frag-ordered ----
    {
#pragma unroll
        for (int nf = 0; nf < 4; ++nf)
#pragma unroll
            for (int rr = 0; rr < 4; ++rr)
                Tt[w * 16 + quad * 4 + rr][nf * 16 + mcol] = f2bf(cv[nf][rr]);  // Tt[d][key]
        __syncthreads();
        {
            const int d = t >> 2, ks = t & 3;
            const uint2 a0 = *(const uint2*)&Tt[d][ks * 16 + 0];
            const uint2 a1 = *(const uint2*)&Tt[d][ks * 16 + 4];
            const uint2 a2 = *(const uint2*)&Tt[d][ks * 16 + 8];
            const uint2 a3 = *(const uint2*)&Tt[d][ks * 16 + 12];
            u16* vdst = vt + (size_t)bh * (72 * 64 * 32);
            const int kb = (n0 >> 5) + (ks >> 1);
            u16* p = &vdst[((size_t)kb * 64 + d) * 32 + (ks & 1) * 16];
            *(uint4*)&p[0] = make_uint4(a0.x, a0.y, a1.x, a1.y);
            *(uint4*)&p[8] = make_uint4(a2.x, a2.y, a3.x, a3.y);
        }
    }
}

// ---------------- Kernel 2: LDS-staged flash attention, 64 q/block, async DMA staging ----------------
// R18: k-split across blocks. R5 (70 µs) is latency-bound with grid 576 =
// 2.25 blocks/CU — not enough independent blocks to overlap the per-tile
// chain. KS=2: grid 1152 = 16 bh x 36 qt x 2 k-halves, 18 tiles/block;
// traffic-NEUTRAL (each (bh,kt) tile still read by exactly 36 blocks —
// unlike R2's 16q split which doubled traffic). Partial O (f32) + lsum to
// workspace; k_merge sums halves + applies beta/normalization. Residency
// becomes LDS-capped at 3 blocks/CU (41,984B), up from 2.25, with 4.5
// blocks/CU of grid to fill the tail. KS=1 = exact R5 path, used as
// fallback when ws_size can't fit the +19.2 MB partial buffers.
template <int KS>
__global__ __launch_bounds__(256) void k_attn(const u16* __restrict__ qkh,
                                              const u16* __restrict__ vt,
                                              const float* __restrict__ null_kv,
                                              const float* __restrict__ nk2b,
                                              const float* __restrict__ sq,
                                              const float* __restrict__ ndot,
                                              u16* __restrict__ ih,
                                              u16* __restrict__ il,
                                              float* __restrict__ pO,
                                              float* __restrict__ pL) {
    const int blk = blockIdx.x;             // KS=1: 576 ; KS=2: 1152
    const int xcd = blk & 7;
    const int j = blk >> 3;
    const int bh = xcd * 2 + (j & 1);       // XCD-local bh pair
    const int r2 = j >> 1;
    const int qt = (KS == 2) ? (r2 >> 1) : r2;   // 0..35
    const int kh = (KS == 2) ? (r2 & 1) : 0;     // k-half
    const int q0 = qt * 64;
    const int b = bh >> 3, h = bh & 7;
    const int t = threadIdx.x;
    const int wave = t >> 6, lane = t & 63;
    const int mcol = lane & 15, quad = lane >> 4;

    const int kt0 = kh * 18;
    const int NTL = (KS == 2) ? 18 : 36;

    // sm layout (u16 units): [0,8192)=K 2 bufs x [64][64]; [8192,16384)=V 2 bufs
    // x [2 sub][64][32]; [16384,20992)=Pt 4 waves x [16][72]. Epilogue aliases
    // the K/V region as f32 scratch.
    __shared__ __align__(16) u16 sm[20992];
    u16* Kls = sm;
    u16* Vls = sm + 8192;
    u16 (*Pt)[72] = (u16(*)[72])(sm + 16384 + wave * 1152);

    const u16* qbase = qkh + (size_t)bh * NPOS * 64;
    const u16* vbase = vt + (size_t)bh * (72 * 64 * 32);
    const float* sqb = sq + (size_t)bh * NPOS;

    const int q16 = q0 + wave * 16;
    const bf16x8 bq00 = *(const bf16x8*)&qbase[(q16 + mcol) * 64 + quad * 8];
    const bf16x8 bq01 = *(const bf16x8*)&qbase[(q16 + mcol) * 64 + 32 + quad * 8];
    const float q2 = sqb[q16 + mcol];
    const int ktm = q16 >> 6;               // k-tile containing the self-masked key
    const int nbm = (q16 >> 4) & 3;

    // ---- staging offsets (u16 units) ----
    // K: wave w covers rows [w*16, w*16+16) as 2 chunks of 8 rows (1KB each).
    //    lane l -> row base+ (l>>3), granule (l&7); source granule ^= (l>>3).
    const int kbase0 = (wave * 16 + 0) * 64;            // LDS chunk base (uniform)
    const int kbase1 = (wave * 16 + 8) * 64;
    const int ksrc0 = (wave * 16 + 0 + (lane >> 3)) * 64 + ((lane & 7) ^ (lane >> 3)) * 8;
    const int ksrc1 = (wave * 16 + 8 + (lane >> 3)) * 64 + ((lane & 7) ^ (lane >> 3)) * 8;
    // V: per sub s, wave w covers rows [w*16, w*16+16) (1KB). lane l -> row
    //    base+(l>>2), granule (l&3); source granule ^= ((l>>3)&3).
    const int vldsb = wave * 512;                       // within a sub (uniform)
    const int vsrc = (wave * 16 + (lane >> 2)) * 32 + ((lane & 3) ^ ((lane >> 3) & 3)) * 8;

    // read-side swizzles
    const int m7 = mcol & 7;
    const int mv = (mcol >> 1) & 3;

    {   // prologue: stage tile kt0 into buf 0
        const u16* kg = qbase + (size_t)kt0 * 4096;
        const u16* vg = vbase + (size_t)kt0 * 4096;
        gl16(kg + ksrc0, Kls + kbase0);
        gl16(kg + ksrc1, Kls + kbase1);
        gl16(vg + vsrc,        Vls + vldsb);
        gl16(vg + 2048 + vsrc, Vls + 2048 + vldsb);
    }

    const bf16x8 ones = {0x3F80, 0x3F80, 0x3F80, 0x3F80, 0x3F80, 0x3F80, 0x3F80, 0x3F80};

    f32x4 oacc[4];
#pragma unroll
    for (int nb = 0; nb < 4; ++nb) oacc[nb] = (f32x4){0.f, 0.f, 0.f, 0.f};
    f32x4 lsum = (f32x4){0.f, 0.f, 0.f, 0.f};

    int p = 0;
#pragma unroll 1
    for (int i = 0; i < NTL; ++i) {
        const int kt = kt0 + i;
        __syncthreads();                    // vmcnt(0) drain -> buf[p] DMA complete
        // k2 loads FIRST (oldest vmcnt slots -> consumed without draining DMAs)
        float4 k2q[4];
#pragma unroll
        for (int nb = 0; nb < 4; ++nb)
            k2q[nb] = *(const float4*)&sqb[kt * 64 + nb * 16 + quad * 4];
        // issue next tile's DMA into buf p^1 (readers finished before barrier)
        if (i + 1 < NTL) {
            const u16* kg = qbase + (size_t)(kt + 1) * 4096;
            const u16* vg = vbase + (size_t)(kt + 1) * 4096;
            const int bb = (p ^ 1) * 4096;
            gl16(kg + ksrc0, Kls + bb + kbase0);
            gl16(kg + ksrc1, Kls + bb + kbase1);
            gl16(vg + vsrc,        Vls + bb + vldsb);
            gl16(vg + 2048 + vsrc, Vls + bb + 2048 + vldsb);
        }

        const u16* Kb = Kls + p * 4096;
        const u16* Vb = Vls + p * 4096;

        bf16x8 bk[4][2];
#pragma unroll
        for (int nb = 0; nb < 4; ++nb) {
            const int rr = (nb * 16 + mcol) * 64;
            bk[nb][0] = *(const bf16x8*)&Kb[rr + ((quad ^ m7)) * 8];
            bk[nb][1] = *(const bf16x8*)&Kb[rr + (((4 + quad) ^ m7)) * 8];
        }

        f32x4 c[4];
#pragma unroll
        for (int nb = 0; nb < 4; ++nb) {
            c[nb] = (f32x4){0.f, 0.f, 0.f, 0.f};
            c[nb] = __builtin_amdgcn_mfma_f32_16x16x32_bf16(bk[nb][0], bq00, c[nb], 0, 0, 0);
            c[nb] = __builtin_amdgcn_mfma_f32_16x16x32_bf16(bk[nb][1], bq01, c[nb], 0, 0, 0);
        }

        bf16x8 bv[4][2];
#pragma unroll
        for (int nb = 0; nb < 4; ++nb) {
            const int rr = (nb * 16 + mcol) * 32 + ((quad ^ mv)) * 8;
            bv[nb][0] = *(const bf16x8*)&Vb[rr];
            bv[nb][1] = *(const bf16x8*)&Vb[2048 + rr];
        }

#pragma unroll
        for (int nb = 0; nb < 4; ++nb) {
            float e[4];
#pragma unroll
            for (int r = 0; r < 4; ++r) {
                const float pre = q2 + ((const float*)&k2q[nb])[r];
                const float d2 = fmaxf(__builtin_fmaf(c[nb][r], -2.0f, pre), 0.0f);
                e[r] = __builtin_amdgcn_exp2f(NEGSL2E * __builtin_amdgcn_sqrtf(d2));
            }
            if (kt == ktm && nb == nbm) {
#pragma unroll
                for (int r = 0; r < 4; ++r)
                    if (quad * 4 + r == mcol) e[r] = 0.0f;   // exp(MASKV) ~ 0
            }
            const u32 p01 = __builtin_amdgcn_perm(__float_as_uint(e[1]), __float_as_uint(e[0]), 0x07060302u);
            const u32 p23 = __builtin_amdgcn_perm(__float_as_uint(e[3]), __float_as_uint(e[2]), 0x07060302u);
            *(uint2*)&Pt[mcol][nb * 16 + quad * 4] = make_uint2(p01, p23);
        }

        const bf16x8 bp00 = *(const bf16x8*)&Pt[mcol][quad * 8];
        const bf16x8 bp01 = *(const bf16x8*)&Pt[mcol][32 + quad * 8];

#pragma unroll
        for (int nb = 0; nb < 4; ++nb) {
            oacc[nb] = __builtin_amdgcn_mfma_f32_16x16x32_bf16(bv[nb][0], bp00, oacc[nb], 0, 0, 0);
            oacc[nb] = __builtin_amdgcn_mfma_f32_16x16x32_bf16(bv[nb][1], bp01, oacc[nb], 0, 0, 0);
        }
        lsum = __builtin_amdgcn_mfma_f32_16x16x32_bf16(ones, bp00, lsum, 0, 0, 0);
        lsum = __builtin_amdgcn_mfma_f32_16x16x32_bf16(ones, bp01, lsum, 0, 0, 0);

        p ^= 1;
    }

    __syncthreads();                        // main loop done; K/V region reusable

    // ---- per-wave finalize: transpose via LDS (alias K/V region) ----
    float* Ofin = (float*)sm + wave * (16 * 68);   // 4 waves x 16 q x 68 f32 = 17.4KB
#pragma unroll
    for (int nb = 0; nb < 4; ++nb)
        *(f32x4*)&Ofin[mcol * 68 + nb * 16 + quad * 4] = oacc[nb];
    if (quad == 0) Ofin[mcol * 68 + 64] = lsum[0];

    {
        const int q = lane >> 2;            // 0..15
        const int d0 = (lane & 3) * 16;     // 0, 16, 32, 48
        const float4 a0 = *(const float4*)&Ofin[q * 68 + d0 + 0];
        const float4 a1 = *(const float4*)&Ofin[q * 68 + d0 + 4];
        const float4 a2 = *(const float4*)&Ofin[q * 68 + d0 + 8];
        const float4 a3 = *(const float4*)&Ofin[q * 68 + d0 + 12];
        const float l = Ofin[q * 68 + 64];
        const int qg = q16 + q;

        if (KS == 2) {
            // raw partials; merge kernel applies beta + normalization
            float* dst = pO + (size_t)kh * 2359296 + ((size_t)bh * NPOS + qg) * 64 + d0;
            *(float4*)&dst[0]  = a0;
            *(float4*)&dst[4]  = a1;
            *(float4*)&dst[8]  = a2;
            *(float4*)&dst[12] = a3;
            if ((lane & 3) == 0)
                pL[(size_t)kh * 36864 + (size_t)bh * NPOS + qg] = l;
        } else {
            const float q2v = sqb[qg];
            const float nd = ndot[(size_t)bh * NPOS + qg];
            const float nk2 = nk2b[h];
            const float d2n = fmaxf(q2v + nk2 - 2.0f * nd, 0.0f);
            const float beta = __expf(-sqrtf(d2n) * SCALE);
            const float ilv = 1.0f / (l + beta);

            const float* nvp = &null_kv[DI + h * 64 + d0];
            const float4 nv0 = *(const float4*)&nvp[0];
            const float4 nv1 = *(const float4*)&nvp[4];
            const float4 nv2 = *(const float4*)&nvp[8];
            const float4 nv3 = *(const float4*)&nvp[12];

            const size_t ob = ((size_t)b * NPOS + qg) * DI + h * 64 + d0;
            float vv[16];
            vv[0]  = (a0.x + beta * nv0.x) * ilv; vv[1]  = (a0.y + beta * nv0.y) * ilv;
            vv[2]  = (a0.z + beta * nv0.z) * ilv; vv[3]  = (a0.w + beta * nv0.w) * ilv;
            vv[4]  = (a1.x + beta * nv1.x) * ilv; vv[5]  = (a1.y + beta * nv1.y) * ilv;
            vv[6]  = (a1.z + beta * nv1.z) * ilv; vv[7]  = (a1.w + beta * nv1.w) * ilv;
            vv[8]  = (a2.x + beta * nv2.x) * ilv; vv[9]  = (a2.y + beta * nv2.y) * ilv;
            vv[10] = (a2.z + beta * nv2.z) * ilv; vv[11] = (a2.w + beta * nv2.w) * ilv;
            vv[12] = (a3.x + beta * nv3.x) * ilv; vv[13] = (a3.y + beta * nv3.y) * ilv;
            vv[14] = (a3.z + beta * nv3.z) * ilv; vv[15] = (a3.w + beta * nv3.w) * ilv;
#pragma unroll
            for (int g = 0; g < 4; ++g) {
                ushort4 hi4, lo4;
                hi4.x = f2bf(vv[g * 4 + 0]); lo4.x = f2bf(vv[g * 4 + 0] - bf2f(hi4.x));
                hi4.y = f2bf(vv[g * 4 + 1]); lo4.y = f2bf(vv[g * 4 + 1] - bf2f(hi4.y));
                hi4.z = f2bf(vv[g * 4 + 2]); lo4.z = f2bf(vv[g * 4 + 2] - bf2f(hi4.z));
                hi4.w = f2bf(vv[g * 4 + 3]); lo4.w = f2bf(vv[g * 4 + 3] - bf2f(hi4.w));
                *(ushort4*)&ih[ob + g * 4] = hi4;
                *(ushort4*)&il[ob + g * 4] = lo4;
            }
        }
    }
}

// ---------------- Kernel 2b: merge k-split partials + beta/normalize -> ih/il ----------------
// 576 blocks x 256 threads = 147456 = 2 * 2304 * 8 heads * 4 d-chunks.
// Decode puts (qg, d-chunk) fastest -> pO reads fully contiguous per wave.
__global__ __launch_bounds__(256) void k_merge(const float* __restrict__ pO,
                                               const float* __restrict__ pL,
                                               const float* __restrict__ null_kv,
                                               const float* __restrict__ nk2b,
                                               const float* __restrict__ sq,
                                               const float* __restrict__ ndot,
                                               u16* __restrict__ ih,
                                               u16* __restrict__ il) {
    const int gid = blockIdx.x * 256 + (int)threadIdx.x;   // 0..147455
    const int d0 = (gid & 3) * 16;
    const int t2 = gid >> 2;                 // 0..36863
    const int bh = t2 / NPOS;                // 0..15
    const int qg = t2 - bh * NPOS;
    const int b = bh >> 3, h = bh & 7;

    const size_t o0 = ((size_t)bh * NPOS + qg) * 64 + d0;
    const size_t o1 = o0 + 2359296;
    const float4 a0 = *(const float4*)&pO[o0 + 0];
    const float4 a1 = *(const float4*)&pO[o0 + 4];
    const float4 a2 = *(const float4*)&pO[o0 + 8];
    const float4 a3 = *(const float4*)&pO[o0 + 12];
    const float4 c0 = *(const float4*)&pO[o1 + 0];
    const float4 c1 = *(const float4*)&pO[o1 + 4];
    const float4 c2 = *(const float4*)&pO[o1 + 8];
    const float4 c3 = *(const float4*)&pO[o1 + 12];
    const float l = pL[(size_t)bh * NPOS + qg] + pL[36864 + (size_t)bh * NPOS + qg];

    const float q2v = sq[(size_t)bh * NPOS + qg];
    const float nd = ndot[(size_t)bh * NPOS + qg];
    const float nk2 = nk2b[h];
    const float d2n = fmaxf(q2v + nk2 - 2.0f * nd, 0.0f);
    const float beta = __expf(-sqrtf(d2n) * SCALE);
    const float ilv = 1.0f / (l + beta);

    const float* nvp = &null_kv[DI + h * 64 + d0];
    const float4 nv0 = *(const float4*)&nvp[0];
    const float4 nv1 = *(const float4*)&nvp[4];
    const float4 nv2 = *(const float4*)&nvp[8];
    const float4 nv3 = *(const float4*)&nvp[12];

    float vv[16];
    vv[0]  = (a0.x + c0.x + beta * nv0.x) * ilv; vv[1]  = (a0.y + c0.y + beta * nv0.y) * ilv;
    vv[2]  = (a0.z + c0.z + beta * nv0.z) * ilv; vv[3]  = (a0.w + c0.w + beta * nv0.w) * ilv;
    vv[4]  = (a1.x + c1.x + beta * nv1.x) * ilv; vv[5]  = (a1.y + c1.y + beta * nv1.y) * ilv;
    vv[6]  = (a1.z + c1.z + beta * nv1.z) * ilv; vv[7]  = (a1.w + c1.w + beta * nv1.w) * ilv;
    vv[8]  = (a2.x + c2.x + beta * nv2.x) * ilv; vv[9]  = (a2.y + c2.y + beta * nv2.y) * ilv;
    vv[10] = (a2.z + c2.z + beta * nv2.z) * ilv; vv[11] = (a2.w + c2.w + beta * nv2.w) * ilv;
    vv[12] = (a3.x + c3.x + beta * nv3.x) * ilv; vv[13] = (a3.y + c3.y + beta * nv3.y) * ilv;
    vv[14] = (a3.z + c3.z + beta * nv3.z) * ilv; vv[15] = (a3.w + c3.w + beta * nv3.w) * ilv;

    const size_t ob = ((size_t)b * NPOS + qg) * DI + h * 64 + d0;
#pragma unroll
    for (int g = 0; g < 4; ++g) {
        ushort4 hi4, lo4;
        hi4.x = f2bf(vv[g * 4 + 0]); lo4.x = f2bf(vv[g * 4 + 0] - bf2f(hi4.x));
        hi4.y = f2bf(vv[g * 4 + 1]); lo4.y = f2bf(vv[g * 4 + 1] - bf2f(hi4.y));
        hi4.z = f2bf(vv[g * 4 + 2]); lo4.z = f2bf(vv[g * 4 + 2] - bf2f(hi4.z));
        hi4.w = f2bf(vv[g * 4 + 3]); lo4.w = f2bf(vv[g * 4 + 3] - bf2f(hi4.w));
        *(ushort4*)&ih[ob + g * 4] = hi4;
        *(ushort4*)&il[ob + g * 4] = lo4;
    }
}

// ---------------- Kernel 3: output projection (split-bf16 MFMA, 32-wide j tiles) ----------------
__global__ __launch_bounds__(256) void k_out(const u16* __restrict__ wo_hi,
                                             const u16* __restrict__ wo_lo,
                                             const u16* __restrict__ ih,
                                             const u16* __restrict__ il,
                                             float* __restrict__ out) {
    const int j0 = blockIdx.x * 32;        // 72 j-tiles of 32 -> 576 blocks
    const int c0 = blockIdx.y * 64;
    const int b  = blockIdx.z;
    const int t  = threadIdx.x;
    const int w = t >> 6, lane = t & 63, mcol = lane & 15, quad = lane >> 4;

    const u16* ah = wo_hi + (size_t)(c0 + w * 16 + mcol) * 512 + quad * 8;
    const u16* al = wo_lo + (size_t)(c0 + w * 16 + mcol) * 512 + quad * 8;
    const u16* xh = ih + ((size_t)b * NPOS + j0 + mcol) * 512 + quad * 8;
    const u16* xl = il + ((size_t)b * NPOS + j0 + mcol) * 512 + quad * 8;

    f32x4 c[2];
#pragma unroll
    for (int nf = 0; nf < 2; ++nf) c[nf] = (f32x4){0.f, 0.f, 0.f, 0.f};
#pragma unroll
    for (int kc = 0; kc < 16; ++kc) {
        const bf16x8 A  = *(const bf16x8*)&ah[kc * 32];
        const bf16x8 Al = *(const bf16x8*)&al[kc * 32];
        bf16x8 Bh[2], Bl[2];
#pragma unroll
        for (int nf = 0; nf < 2; ++nf) {
            Bh[nf] = *(const bf16x8*)&xh[(size_t)nf * 16 * 512 + kc * 32];
            Bl[nf] = *(const bf16x8*)&xl[(size_t)nf * 16 * 512 + kc * 32];
        }
#pragma unroll
        for (int nf = 0; nf < 2; ++nf) {
            c[nf] = __builtin_amdgcn_mfma_f32_16x16x32_bf16(A,  Bh[nf], c[nf], 0, 0, 0);
            c[nf] = __builtin_amdgcn_mfma_f32_16x16x32_bf16(A,  Bl[nf], c[nf], 0, 0, 0);
            c[nf] = __builtin_amdgcn_mfma_f32_16x16x32_bf16(Al, Bh[nf], c[nf], 0, 0, 0);
        }
    }
    float* ob = out + ((size_t)b * CC + c0 + w * 16) * NPOS + j0;
#pragma unroll
    for (int nf = 0; nf < 2; ++nf)
#pragma unroll
        for (int r = 0; r < 4; ++r)
            ob[(size_t)(quad * 4 + r) * NPOS + nf * 16 + mcol] = c[nf][r];
}

extern "C" void kernel_launch(void* const* d_in, const int* in_sizes, int n_in,
                              void* d_out, int out_size, void* d_ws, size_t ws_size,
                              hipStream_t stream) {
    const float* fmap    = (const float*)d_in[0];
    const float* gamma   = (const float*)d_in[1];
    const float* w_qk    = (const float*)d_in[2];
    const float* w_v     = (const float*)d_in[3];
    const float* null_kv = (const float*)d_in[4];
    const float* w_out   = (const float*)d_in[5];
    float* out = (float*)d_out;

    u16* ws16 = (u16*)d_ws;
    u16* qkh    = ws16;                     // 16*2304*64  = 2,359,296 u16
    u16* vtb    = qkh + 2359296;            // 16*72*64*32 = 2,359,296
    u16* in_hi  = vtb + 2359296;            // 2*2304*512  = 2,359,296
    u16* in_lo  = in_hi + 2359296;          //               2,359,296
    u16* wo_hi  = in_lo + 2359296;          // 256*512     =   131,072
    u16* wo_lo  = wo_hi + 131072;           //                 131,072
    float* sqbuf = (float*)(wo_lo + 131072);    // 36,864 f32
    float* ndbuf = sqbuf + 36864;               // 36,864
    float* nk2b  = ndbuf + 36864;               // 8
    // base total ~19.7 MB; k-split partials below need +19.2 MB
    float* pOws  = nk2b + 8;                    // 2*16*2304*64 = 4,718,592 f32
    float* pLws  = pOws + 4718592;              // 2*16*2304    =    73,728 f32
    const size_t need_split = (size_t)((char*)(pLws + 73728) - (char*)d_ws);

    hipLaunchKernelGGL(k_proj, dim3(648),       dim3(256), 0, stream,
                       fmap, gamma, w_qk, w_v, w_out, null_kv, qkh, vtb, sqbuf, ndbuf, nk2b, wo_hi, wo_lo);
    if (ws_size >= need_split) {
        hipLaunchKernelGGL(HIP_KERNEL_NAME(k_attn<2>), dim3(1152), dim3(256), 0, stream,
                           qkh, vtb, null_kv, nk2b, sqbuf, ndbuf, in_hi, in_lo, pOws, pLws);
        hipLaunchKernelGGL(k_merge, dim3(576),  dim3(256), 0, stream,
                           pOws, pLws, null_kv, nk2b, sqbuf, ndbuf, in_hi, in_lo);
    } else {
        hipLaunchKernelGGL(HIP_KERNEL_NAME(k_attn<1>), dim3(576), dim3(256), 0, stream,
                           qkh, vtb, null_kv, nk2b, sqbuf, ndbuf, in_hi, in_lo, pOws, pLws);
    }
    hipLaunchKernelGGL(k_out,  dim3(72, 4, 2),  dim3(256), 0, stream,
                       wo_hi, wo_lo, in_hi, in_lo, out);
}

// Round 7
// 155.718 us; speedup vs baseline: 1.2535x; 1.1469x over previous
//
#include <hip/hip_runtime.h>
#include <math.h>

#define NPOS 2304   // 48*48
#define CC   256    // DIM
#define DI   512    // HEADS*DIM_HEAD
#define NT   36     // NPOS/64
#define SCALE 0.125f
#define MASKV -100.0f
// exp(-SCALE*sqrt(d2)) = exp2(-SCALE*log2(e)*sqrt(d2))
#define NEGSL2E (-0.18033688011112042f)

typedef __attribute__((ext_vector_type(8))) short bf16x8;  // 8 bf16 (4 VGPRs)
typedef __attribute__((ext_vector_type(4))) float f32x4;   // MFMA C/D frag
typedef unsigned short u16;
typedef unsigned int u32;

__device__ inline u16 f2bf(float f) {
    union { float f; unsigned int u; } v; v.f = f;
    return (u16)((v.u + 0x7fffu + ((v.u >> 16) & 1u)) >> 16);
}
__device__ inline float bf2f(u16 h) { return __uint_as_float(((u32)h) << 16); }

// assemble a bf16x8 frag from 8-byte-aligned LDS via two b64 reads
__device__ inline bf16x8 ld_x8(const u16* p) {
    union { bf16x8 v; uint2 d[2]; } u;
    u.d[0] = *(const uint2*)(p + 0);
    u.d[1] = *(const uint2*)(p + 4);
    return u.v;
}

// async global->LDS DMA, 16B per lane (dest = wave-uniform base + lane*16)
__device__ __forceinline__ void gl16(const u16* g, u16* l) {
    __builtin_amdgcn_global_load_lds(
        (const __attribute__((address_space(1))) void*)g,
        (__attribute__((address_space(3))) void*)l, 16, 0, 0);
}

// ---------------- Kernel 0: one-time weight prep ----------------
// R19: weights were f32->bf16 converted PER CONSUMER BLOCK (k_proj: each
// head slice converted 36x; ~384 VALU ops/thread in the hot loop + 2x weight
// bytes). Convert once here; also absorbs the w_out hi/lo split (was 72 extra
// k_proj blocks). No input dependencies -> runs first, ~4 µs.
__global__ __launch_bounds__(256) void k_prep(const float* __restrict__ wqk,
                                              const float* __restrict__ wv,
                                              const float* __restrict__ wout,
                                              u16* __restrict__ wqkh,
                                              u16* __restrict__ wvh,
                                              u16* __restrict__ wo_hi,
                                              u16* __restrict__ wo_lo) {
    const int blk = blockIdx.x;            // 384
    const int t = threadIdx.x;
    if (blk < 128) {                       // wqk -> bf16 (32768 float4)
        const int k = blk * 256 + t;
        const float4 v = ((const float4*)wqk)[k];
        ushort4 h4;
        h4.x = f2bf(v.x); h4.y = f2bf(v.y); h4.z = f2bf(v.z); h4.w = f2bf(v.w);
        ((ushort4*)wqkh)[k] = h4;
    } else if (blk < 256) {                // wv -> bf16
        const int k = (blk - 128) * 256 + t;
        const float4 v = ((const float4*)wv)[k];
        ushort4 h4;
        h4.x = f2bf(v.x); h4.y = f2bf(v.y); h4.z = f2bf(v.z); h4.w = f2bf(v.w);
        ((ushort4*)wvh)[k] = h4;
    } else {                               // wout -> hi/lo split
        const int k = (blk - 256) * 256 + t;
        const float4 v = ((const float4*)wout)[k];
        ushort4 h4, l4;
        h4.x = f2bf(v.x); l4.x = f2bf(v.x - bf2f(h4.x));
        h4.y = f2bf(v.y); l4.y = f2bf(v.y - bf2f(h4.y));
        h4.z = f2bf(v.z); l4.z = f2bf(v.z - bf2f(h4.z));
        h4.w = f2bf(v.w); l4.w = f2bf(v.w - bf2f(h4.w));
        ((ushort4*)wo_hi)[k] = h4;
        ((ushort4*)wo_lo)[k] = l4;
    }
}

// ---------------- Kernel 1: fused rmsnorm + paired qk/v MFMA projection ----------------
// XCD-aligned 1D grid (576): xcd=blk&7 produces bh=xcd*2+(r&1), matching
// k_attn's consumer swizzle. R19: weights arrive pre-converted bf16 (k_prep),
// phase B loads bf16x8 directly — no per-block f32->bf16, half the weight bytes.
__global__ __launch_bounds__(256) void k_proj(const float* __restrict__ fmap,
                                              const float* __restrict__ gamma,
                                              const u16* __restrict__ wqkh,
                                              const u16* __restrict__ wvh,
                                              const float* __restrict__ null_kv,
                                              u16* __restrict__ qkh,
                                              u16* __restrict__ vt,
                                              float* __restrict__ sq,
                                              float* __restrict__ ndot,
                                              float* __restrict__ nk2b) {
    const int blk = blockIdx.x;
    const int xcd = blk & 7;
    const int r   = blk >> 3;             // 0..71
    const int bh  = xcd * 2 + (r & 1);    // 0..15
    const int b   = bh >> 3;
    const int oy  = bh & 7;               // head
    const int n0  = (r >> 1) * 64;        // 36 position tiles

    const int t  = threadIdx.x;
    const int w = t >> 6, lane = t & 63, mcol = lane & 15, quad = lane >> 4;
    const int tx = t & 63, ty = t >> 6;

    __shared__ u16 X[64][260];            // [pos][chan]; dword pitch 130, rows 8B-aligned
    __shared__ float red[4][64];
    __shared__ float inv_s[64];
    __shared__ float gs[256];
    __shared__ float sqp[4][64], ndp[4][64];
    u16 (*Tt)[68] = (u16(*)[68])X;        // aliased after phase B

    // ---- phase A: rmsnorm, fmap held in registers (single global pass) ----
    gs[t] = gamma[t];
    const float* fb = fmap + (size_t)b * CC * NPOS;
    float v64[64];
#pragma unroll
    for (int i = 0; i < 64; ++i)
        v64[i] = fb[(ty * 64 + i) * NPOS + n0 + tx];
    float s = 0.0f;
#pragma unroll
    for (int i = 0; i < 64; ++i) s += v64[i] * v64[i];
    red[ty][tx] = s;
    __syncthreads();
    if (t < 64) {
        const float tt = red[0][t] + red[1][t] + red[2][t] + red[3][t];
        inv_s[t] = 16.0f / fmaxf(sqrtf(tt), 1e-12f);
    }
    __syncthreads();
    const float iv = inv_s[tx];
#pragma unroll
    for (int i = 0; i < 64; i += 2) {
        const int c = ty * 64 + i;
        const float v0 = v64[i] * iv * gs[c];
        const float v1 = v64[i + 1] * iv * gs[c + 1];
        *(u32*)&X[tx][c] = (u32)f2bf(v0) | ((u32)f2bf(v1) << 16);   // bank 2-way: free
    }
    if (blk == 0 && t < 8) {
        float s2 = 0.0f;
#pragma unroll 8
        for (int d = 0; d < 64; ++d) { const float x = null_kv[t * 64 + d]; s2 += x * x; }
        nk2b[t] = s2;
    }
    __syncthreads();

    // ---- phase B (dual): one X frag read feeds qk-head AND v-head MFMA ----
    const size_t wroff = (size_t)(oy * 64 + w * 16 + mcol) * 256 + quad * 8;
    const u16* wrq = wqkh + wroff;
    const u16* wrv = wvh + wroff;

    f32x4 cq[4], cv[4];
#pragma unroll
    for (int nf = 0; nf < 4; ++nf) {
        cq[nf] = (f32x4){0.f, 0.f, 0.f, 0.f};
        cv[nf] = (f32x4){0.f, 0.f, 0.f, 0.f};
    }
#pragma unroll
    for (int kc = 0; kc < 8; ++kc) {
        const bf16x8 aq = *(const bf16x8*)&wrq[kc * 32];
        const bf16x8 av = *(const bf16x8*)&wrv[kc * 32];
        bf16x8 xB[4];
#pragma unroll
        for (int nf = 0; nf < 4; ++nf)
            xB[nf] = ld_x8(&X[nf * 16 + mcol][kc * 32 + quad * 8]);
#pragma unroll
        for (int nf = 0; nf < 4; ++nf) {
            cq[nf] = __builtin_amdgcn_mfma_f32_16x16x32_bf16(aq, xB[nf], cq[nf], 0, 0, 0);
            cv[nf] = __builtin_amdgcn_mfma_f32_16x16x32_bf16(av, xB[nf], cv[nf], 0, 0, 0);
        }
    }
    __syncthreads();   // all X reads done; Tt alias safe

    // ---- epilogue 1: qk head -> qkh + sq/ndot ----
    {
        const int h = oy;   // d = w*16 + quad*4 + r, n = n0 + nf*16 + mcol
        const float4 nk4 = *(const float4*)&null_kv[h * 64 + w * 16 + quad * 4];
        float sv[4], nd[4];
#pragma unroll
        for (int nf = 0; nf < 4; ++nf) {
            sv[nf] = cq[nf][0] * cq[nf][0] + cq[nf][1] * cq[nf][1] + cq[nf][2] * cq[nf][2] + cq[nf][3] * cq[nf][3];
            nd[nf] = cq[nf][0] * nk4.x + cq[nf][1] * nk4.y + cq[nf][2] * nk4.z + cq[nf][3] * nk4.w;
        }
#pragma unroll
        for (int mk = 16; mk <= 32; mk <<= 1)
#pragma unroll
            for (int nf = 0; nf < 4; ++nf) {
                sv[nf] += __shfl_xor(sv[nf], mk);
                nd[nf] += __shfl_xor(nd[nf], mk);
            }
        if (quad == 0) {
#pragma unroll
            for (int nf = 0; nf < 4; ++nf) {
                sqp[w][nf * 16 + mcol] = sv[nf];
                ndp[w][nf * 16 + mcol] = nd[nf];
            }
        }
#pragma unroll
        for (int nf = 0; nf < 4; ++nf) {
            ushort4 r4;
            r4.x = f2bf(cq[nf][0]); r4.y = f2bf(cq[nf][1]);
            r4.z = f2bf(cq[nf][2]); r4.w = f2bf(cq[nf][3]);
            *(ushort4*)&Tt[nf * 16 + mcol][w * 16 + quad * 4] = r4;   // Tt[n][d]
        }
        __syncthreads();
        {
            const int n = t >> 2, ds = (t & 3) * 16;
            const uint2 r0 = *(const uint2*)&Tt[n][ds + 0];
            const uint2 r1 = *(const uint2*)&Tt[n][ds + 4];
            const uint2 r2 = *(const uint2*)&Tt[n][ds + 8];
            const uint2 r3 = *(const uint2*)&Tt[n][ds + 12];
            u16* dst = qkh + (((size_t)bh) * NPOS + n0 + n) * 64 + ds;
            *(uint4*)&dst[0] = make_uint4(r0.x, r0.y, r1.x, r1.y);
            *(uint4*)&dst[8] = make_uint4(r2.x, r2.y, r3.x, r3.y);
        }
        if (t < 64) {
            sq  [((size_t)bh) * NPOS + n0 + t] = sqp[0][t] + sqp[1][t] + sqp[2][t] + sqp[3][t];
            ndot[((size_t)bh) * NPOS + n0 + t] = ndp[0][t] + ndp[1][t] + ndp[2][t] + ndp[3][t];
        }
    }
    __syncthreads();   // qk readback done before Tt reuse

    // ---- epilogue 2: v head -> vt frag-ordered ----
    {
#pragma unroll
        for (int nf = 0; nf < 4; ++nf)
#pragma unroll
            for (int rr = 0; rr < 4; ++rr)
                Tt[w * 16 + quad * 4 + rr][nf * 16 + mcol] = f2bf(cv[nf][rr]);  // Tt[d][key]
        __syncthreads();
        {
            const int d = t >> 2, ks = t & 3;
            const uint2 a0 = *(const uint2*)&Tt[d][ks * 16 + 0];
            const uint2 a1 = *(const uint2*)&Tt[d][ks * 16 + 4];
            const uint2 a2 = *(const uint2*)&Tt[d][ks * 16 + 8];
            const uint2 a3 = *(const uint2*)&Tt[d][ks * 16 + 12];
            u16* vdst = vt + (size_t)bh * (72 * 64 * 32);
            const int kb = (n0 >> 5) + (ks >> 1);
            u16* p = &vdst[((size_t)kb * 64 + d) * 32 + (ks & 1) * 16];
            *(uint4*)&p[0] = make_uint4(a0.x, a0.y, a1.x, a1.y);
            *(uint4*)&p[8] = make_uint4(a2.x, a2.y, a3.x, a3.y);
        }
    }
}

// ---------------- Kernel 2: LDS-staged flash attention, 64 q/block, async DMA staging ----------------
// (unchanged from R6: KS=2 k-split, gl16 staging, XOR swizzle; KS=1 fallback)
template <int KS>
__global__ __launch_bounds__(256) void k_attn(const u16* __restrict__ qkh,
                                              const u16* __restrict__ vt,
                                              const float* __restrict__ null_kv,
                                              const float* __restrict__ nk2b,
                                              const float* __restrict__ sq,
                                              const float* __restrict__ ndot,
                                              u16* __restrict__ ih,
                                              u16* __restrict__ il,
                                              float* __restrict__ pO,
                                              float* __restrict__ pL) {
    const int blk = blockIdx.x;             // KS=1: 576 ; KS=2: 1152
    const int xcd = blk & 7;
    const int j = blk >> 3;
    const int bh = xcd * 2 + (j & 1);       // XCD-local bh pair
    const int r2 = j >> 1;
    const int qt = (KS == 2) ? (r2 >> 1) : r2;   // 0..35
    const int kh = (KS == 2) ? (r2 & 1) : 0;     // k-half
    const int q0 = qt * 64;
    const int b = bh >> 3, h = bh & 7;
    const int t = threadIdx.x;
    const int wave = t >> 6, lane = t & 63;
    const int mcol = lane & 15, quad = lane >> 4;

    const int kt0 = kh * 18;
    const int NTL = (KS == 2) ? 18 : 36;

    __shared__ __align__(16) u16 sm[20992];
    u16* Kls = sm;
    u16* Vls = sm + 8192;
    u16 (*Pt)[72] = (u16(*)[72])(sm + 16384 + wave * 1152);

    const u16* qbase = qkh + (size_t)bh * NPOS * 64;
    const u16* vbase = vt + (size_t)bh * (72 * 64 * 32);
    const float* sqb = sq + (size_t)bh * NPOS;

    const int q16 = q0 + wave * 16;
    const bf16x8 bq00 = *(const bf16x8*)&qbase[(q16 + mcol) * 64 + quad * 8];
    const bf16x8 bq01 = *(const bf16x8*)&qbase[(q16 + mcol) * 64 + 32 + quad * 8];
    const float q2 = sqb[q16 + mcol];
    const int ktm = q16 >> 6;               // k-tile containing the self-masked key
    const int nbm = (q16 >> 4) & 3;

    const int kbase0 = (wave * 16 + 0) * 64;
    const int kbase1 = (wave * 16 + 8) * 64;
    const int ksrc0 = (wave * 16 + 0 + (lane >> 3)) * 64 + ((lane & 7) ^ (lane >> 3)) * 8;
    const int ksrc1 = (wave * 16 + 8 + (lane >> 3)) * 64 + ((lane & 7) ^ (lane >> 3)) * 8;
    const int vldsb = wave * 512;
    const int vsrc = (wave * 16 + (lane >> 2)) * 32 + ((lane & 3) ^ ((lane >> 3) & 3)) * 8;

    const int m7 = mcol & 7;
    const int mv = (mcol >> 1) & 3;

    {   // prologue: stage tile kt0 into buf 0
        const u16* kg = qbase + (size_t)kt0 * 4096;
        const u16* vg = vbase + (size_t)kt0 * 4096;
        gl16(kg + ksrc0, Kls + kbase0);
        gl16(kg + ksrc1, Kls + kbase1);
        gl16(vg + vsrc,        Vls + vldsb);
        gl16(vg + 2048 + vsrc, Vls + 2048 + vldsb);
    }

    const bf16x8 ones = {0x3F80, 0x3F80, 0x3F80, 0x3F80, 0x3F80, 0x3F80, 0x3F80, 0x3F80};

    f32x4 oacc[4];
#pragma unroll
    for (int nb = 0; nb < 4; ++nb) oacc[nb] = (f32x4){0.f, 0.f, 0.f, 0.f};
    f32x4 lsum = (f32x4){0.f, 0.f, 0.f, 0.f};

    int p = 0;
#pragma unroll 1
    for (int i = 0; i < NTL; ++i) {
        const int kt = kt0 + i;
        __syncthreads();                    // vmcnt(0) drain -> buf[p] DMA complete
        float4 k2q[4];
#pragma unroll
        for (int nb = 0; nb < 4; ++nb)
            k2q[nb] = *(const float4*)&sqb[kt * 64 + nb * 16 + quad * 4];
        if (i + 1 < NTL) {
            const u16* kg = qbase + (size_t)(kt + 1) * 4096;
            const u16* vg = vbase + (size_t)(kt + 1) * 4096;
            const int bb = (p ^ 1) * 4096;
            gl16(kg + ksrc0, Kls + bb + kbase0);
            gl16(kg + ksrc1, Kls + bb + kbase1);
            gl16(vg + vsrc,        Vls + bb + vldsb);
            gl16(vg + 2048 + vsrc, Vls + bb + 2048 + vldsb);
        }

        const u16* Kb = Kls + p * 4096;
        const u16* Vb = Vls + p * 4096;

        bf16x8 bk[4][2];
#pragma unroll
        for (int nb = 0; nb < 4; ++nb) {
            const int rr = (nb * 16 + mcol) * 64;
            bk[nb][0] = *(const bf16x8*)&Kb[rr + ((quad ^ m7)) * 8];
            bk[nb][1] = *(const bf16x8*)&Kb[rr + (((4 + quad) ^ m7)) * 8];
        }

        f32x4 c[4];
#pragma unroll
        for (int nb = 0; nb < 4; ++nb) {
            c[nb] = (f32x4){0.f, 0.f, 0.f, 0.f};
            c[nb] = __builtin_amdgcn_mfma_f32_16x16x32_bf16(bk[nb][0], bq00, c[nb], 0, 0, 0);
            c[nb] = __builtin_amdgcn_mfma_f32_16x16x32_bf16(bk[nb][1], bq01, c[nb], 0, 0, 0);
        }

        bf16x8 bv[4][2];
#pragma unroll
        for (int nb = 0; nb < 4; ++nb) {
            const int rr = (nb * 16 + mcol) * 32 + ((quad ^ mv)) * 8;
            bv[nb][0] = *(const bf16x8*)&Vb[rr];
            bv[nb][1] = *(const bf16x8*)&Vb[2048 + rr];
        }

#pragma unroll
        for (int nb = 0; nb < 4; ++nb) {
            float e[4];
#pragma unroll
            for (int r = 0; r < 4; ++r) {
                const float pre = q2 + ((const float*)&k2q[nb])[r];
                const float d2 = fmaxf(__builtin_fmaf(c[nb][r], -2.0f, pre), 0.0f);
                e[r] = __builtin_amdgcn_exp2f(NEGSL2E * __builtin_amdgcn_sqrtf(d2));
            }
            if (kt == ktm && nb == nbm) {
#pragma unroll
                for (int r = 0; r < 4; ++r)
                    if (quad * 4 + r == mcol) e[r] = 0.0f;   // exp(MASKV) ~ 0
            }
            const u32 p01 = __builtin_amdgcn_perm(__float_as_uint(e[1]), __float_as_uint(e[0]), 0x07060302u);
            const u32 p23 = __builtin_amdgcn_perm(__float_as_uint(e[3]), __float_as_uint(e[2]), 0x07060302u);
            *(uint2*)&Pt[mcol][nb * 16 + quad * 4] = make_uint2(p01, p23);
        }

        const bf16x8 bp00 = *(const bf16x8*)&Pt[mcol][quad * 8];
        const bf16x8 bp01 = *(const bf16x8*)&Pt[mcol][32 + quad * 8];

#pragma unroll
        for (int nb = 0; nb < 4; ++nb) {
            oacc[nb] = __builtin_amdgcn_mfma_f32_16x16x32_bf16(bv[nb][0], bp00, oacc[nb], 0, 0, 0);
            oacc[nb] = __builtin_amdgcn_mfma_f32_16x16x32_bf16(bv[nb][1], bp01, oacc[nb], 0, 0, 0);
        }
        lsum = __builtin_amdgcn_mfma_f32_16x16x32_bf16(ones, bp00, lsum, 0, 0, 0);
        lsum = __builtin_amdgcn_mfma_f32_16x16x32_bf16(ones, bp01, lsum, 0, 0, 0);

        p ^= 1;
    }

    __syncthreads();                        // main loop done; K/V region reusable

    float* Ofin = (float*)sm + wave * (16 * 68);
#pragma unroll
    for (int nb = 0; nb < 4; ++nb)
        *(f32x4*)&Ofin[mcol * 68 + nb * 16 + quad * 4] = oacc[nb];
    if (quad == 0) Ofin[mcol * 68 + 64] = lsum[0];

    {
        const int q = lane >> 2;            // 0..15
        const int d0 = (lane & 3) * 16;     // 0, 16, 32, 48
        const float4 a0 = *(const float4*)&Ofin[q * 68 + d0 + 0];
        const float4 a1 = *(const float4*)&Ofin[q * 68 + d0 + 4];
        const float4 a2 = *(const float4*)&Ofin[q * 68 + d0 + 8];
        const float4 a3 = *(const float4*)&Ofin[q * 68 + d0 + 12];
        const float l = Ofin[q * 68 + 64];
        const int qg = q16 + q;

        if (KS == 2) {
            float* dst = pO + (size_t)kh * 2359296 + ((size_t)bh * NPOS + qg) * 64 + d0;
            *(float4*)&dst[0]  = a0;
            *(float4*)&dst[4]  = a1;
            *(float4*)&dst[8]  = a2;
            *(float4*)&dst[12] = a3;
            if ((lane & 3) == 0)
                pL[(size_t)kh * 36864 + (size_t)bh * NPOS + qg] = l;
        } else {
            const float q2v = sqb[qg];
            const float nd = ndot[(size_t)bh * NPOS + qg];
            const float nk2 = nk2b[h];
            const float d2n = fmaxf(q2v + nk2 - 2.0f * nd, 0.0f);
            const float beta = __expf(-sqrtf(d2n) * SCALE);
            const float ilv = 1.0f / (l + beta);

            const float* nvp = &null_kv[DI + h * 64 + d0];
            const float4 nv0 = *(const float4*)&nvp[0];
            const float4 nv1 = *(const float4*)&nvp[4];
            const float4 nv2 = *(const float4*)&nvp[8];
            const float4 nv3 = *(const float4*)&nvp[12];

            const size_t ob = ((size_t)b * NPOS + qg) * DI + h * 64 + d0;
            float vv[16];
            vv[0]  = (a0.x + beta * nv0.x) * ilv; vv[1]  = (a0.y + beta * nv0.y) * ilv;
            vv[2]  = (a0.z + beta * nv0.z) * ilv; vv[3]  = (a0.w + beta * nv0.w) * ilv;
            vv[4]  = (a1.x + beta * nv1.x) * ilv; vv[5]  = (a1.y + beta * nv1.y) * ilv;
            vv[6]  = (a1.z + beta * nv1.z) * ilv; vv[7]  = (a1.w + beta * nv1.w) * ilv;
            vv[8]  = (a2.x + beta * nv2.x) * ilv; vv[9]  = (a2.y + beta * nv2.y) * ilv;
            vv[10] = (a2.z + beta * nv2.z) * ilv; vv[11] = (a2.w + beta * nv2.w) * ilv;
            vv[12] = (a3.x + beta * nv3.x) * ilv; vv[13] = (a3.y + beta * nv3.y) * ilv;
            vv[14] = (a3.z + beta * nv3.z) * ilv; vv[15] = (a3.w + beta * nv3.w) * ilv;
#pragma unroll
            for (int g = 0; g < 4; ++g) {
                ushort4 hi4, lo4;
                hi4.x = f2bf(vv[g * 4 + 0]); lo4.x = f2bf(vv[g * 4 + 0] - bf2f(hi4.x));
                hi4.y = f2bf(vv[g * 4 + 1]); lo4.y = f2bf(vv[g * 4 + 1] - bf2f(hi4.y));
                hi4.z = f2bf(vv[g * 4 + 2]); lo4.z = f2bf(vv[g * 4 + 2] - bf2f(hi4.z));
                hi4.w = f2bf(vv[g * 4 + 3]); lo4.w = f2bf(vv[g * 4 + 3] - bf2f(hi4.w));
                *(ushort4*)&ih[ob + g * 4] = hi4;
                *(ushort4*)&il[ob + g * 4] = lo4;
            }
        }
    }
}

// ---------------- Kernel 2b: merge k-split partials + beta/normalize -> ih/il ----------------
__global__ __launch_bounds__(256) void k_merge(const float* __restrict__ pO,
                                               const float* __restrict__ pL,
                                               const float* __restrict__ null_kv,
                                               const float* __restrict__ nk2b,
                                               const float* __restrict__ sq,
                                               const float* __restrict__ ndot,
                                               u16* __restrict__ ih,
                                               u16* __restrict__ il) {
    const int gid = blockIdx.x * 256 + (int)threadIdx.x;   // 0..147455
    const int d0 = (gid & 3) * 16;
    const int t2 = gid >> 2;                 // 0..36863
    const int bh = t2 / NPOS;                // 0..15
    const int qg = t2 - bh * NPOS;
    const int b = bh >> 3, h = bh & 7;

    const size_t o0 = ((size_t)bh * NPOS + qg) * 64 + d0;
    const size_t o1 = o0 + 2359296;
    const float4 a0 = *(const float4*)&pO[o0 + 0];
    const float4 a1 = *(const float4*)&pO[o0 + 4];
    const float4 a2 = *(const float4*)&pO[o0 + 8];
    const float4 a3 = *(const float4*)&pO[o0 + 12];
    const float4 c0 = *(const float4*)&pO[o1 + 0];
    const float4 c1 = *(const float4*)&pO[o1 + 4];
    const float4 c2 = *(const float4*)&pO[o1 + 8];
    const float4 c3 = *(const float4*)&pO[o1 + 12];
    const float l = pL[(size_t)bh * NPOS + qg] + pL[36864 + (size_t)bh * NPOS + qg];

    const float q2v = sq[(size_t)bh * NPOS + qg];
    const float nd = ndot[(size_t)bh * NPOS + qg];
    const float nk2 = nk2b[h];
    const float d2n = fmaxf(q2v + nk2 - 2.0f * nd, 0.0f);
    const float beta = __expf(-sqrtf(d2n) * SCALE);
    const float ilv = 1.0f / (l + beta);

    const float* nvp = &null_kv[DI + h * 64 + d0];
    const float4 nv0 = *(const float4*)&nvp[0];
    const float4 nv1 = *(const float4*)&nvp[4];
    const float4 nv2 = *(const float4*)&nvp[8];
    const float4 nv3 = *(const float4*)&nvp[12];

    float vv[16];
    vv[0]  = (a0.x + c0.x + beta * nv0.x) * ilv; vv[1]  = (a0.y + c0.y + beta * nv0.y) * ilv;
    vv[2]  = (a0.z + c0.z + beta * nv0.z) * ilv; vv[3]  = (a0.w + c0.w + beta * nv0.w) * ilv;
    vv[4]  = (a1.x + c1.x + beta * nv1.x) * ilv; vv[5]  = (a1.y + c1.y + beta * nv1.y) * ilv;
    vv[6]  = (a1.z + c1.z + beta * nv1.z) * ilv; vv[7]  = (a1.w + c1.w + beta * nv1.w) * ilv;
    vv[8]  = (a2.x + c2.x + beta * nv2.x) * ilv; vv[9]  = (a2.y + c2.y + beta * nv2.y) * ilv;
    vv[10] = (a2.z + c2.z + beta * nv2.z) * ilv; vv[11] = (a2.w + c2.w + beta * nv2.w) * ilv;
    vv[12] = (a3.x + c3.x + beta * nv3.x) * ilv; vv[13] = (a3.y + c3.y + beta * nv3.y) * ilv;
    vv[14] = (a3.z + c3.z + beta * nv3.z) * ilv; vv[15] = (a3.w + c3.w + beta * nv3.w) * ilv;

    const size_t ob = ((size_t)b * NPOS + qg) * DI + h * 64 + d0;
#pragma unroll
    for (int g = 0; g < 4; ++g) {
        ushort4 hi4, lo4;
        hi4.x = f2bf(vv[g * 4 + 0]); lo4.x = f2bf(vv[g * 4 + 0] - bf2f(hi4.x));
        hi4.y = f2bf(vv[g * 4 + 1]); lo4.y = f2bf(vv[g * 4 + 1] - bf2f(hi4.y));
        hi4.z = f2bf(vv[g * 4 + 2]); lo4.z = f2bf(vv[g * 4 + 2] - bf2f(hi4.z));
        hi4.w = f2bf(vv[g * 4 + 3]); lo4.w = f2bf(vv[g * 4 + 3] - bf2f(hi4.w));
        *(ushort4*)&ih[ob + g * 4] = hi4;
        *(ushort4*)&il[ob + g * 4] = lo4;
    }
}

// ---------------- Kernel 3: output projection, LDS-staged B (shared across waves) ----------------
// R19: xh/xl depend only on mcol, not the wave index -> all 4 waves issued
// IDENTICAL B reads (~147 MB of L2 traffic, 4x redundant). Stage B per 2-kc
// phase into double-buffered LDS via gl16 DMA (k_attn's proven pattern) with
// the K-style XOR swizzle (granule ^= row&7, both-sides involution; read is
// 2-way max = free). A reads stay direct (per-wave distinct, streamed).
// Accumulation order per c[nf] unchanged -> bit-identical results.
__global__ __launch_bounds__(256) void k_out(const u16* __restrict__ wo_hi,
                                             const u16* __restrict__ wo_lo,
                                             const u16* __restrict__ ih,
                                             const u16* __restrict__ il,
                                             float* __restrict__ out) {
    const int j0 = blockIdx.x * 32;        // 72 j-tiles of 32 -> 576 blocks
    const int c0 = blockIdx.y * 64;
    const int b  = blockIdx.z;
    const int t  = threadIdx.x;
    const int w = t >> 6, lane = t & 63, mcol = lane & 15, quad = lane >> 4;

    // [buf][hi/lo][32 j][64 k] u16 = 16 KB
    __shared__ __align__(16) u16 Bst[2][2][32][64];

    const u16* ah = wo_hi + (size_t)(c0 + w * 16 + mcol) * 512 + quad * 8;
    const u16* al = wo_lo + (size_t)(c0 + w * 16 + mcol) * 512 + quad * 8;

    // staging: wave w stages rows 8w..8w+7 (row&7 == lane>>3) of hi and lo.
    // lane -> LDS granule lane&7 of row 8w+(lane>>3); source granule XOR'd.
    const size_t bsrc_row = (size_t)b * NPOS + j0 + w * 8 + (lane >> 3);
    const int bsg = ((lane & 7) ^ (lane >> 3)) * 8;
    const u16* bsrc_h = ih + bsrc_row * 512 + bsg;
    const u16* bsrc_l = il + bsrc_row * 512 + bsg;
    u16* bdst_h = &Bst[0][0][w * 8][0];
    u16* bdst_l = &Bst[0][1][w * 8][0];

    gl16(bsrc_h, bdst_h);                  // phase 0 -> buf 0
    gl16(bsrc_l, bdst_l);

    f32x4 c[2];
    c[0] = (f32x4){0.f, 0.f, 0.f, 0.f};
    c[1] = (f32x4){0.f, 0.f, 0.f, 0.f};

    int p = 0;
#pragma unroll 1
    for (int ph = 0; ph < 8; ++ph) {
        __syncthreads();                   // vmcnt(0) drain -> buf[p] complete
        if (ph + 1 < 8) {
            const int ko = (ph + 1) * 64;
            gl16(bsrc_h + ko, bdst_h + (p ^ 1) * 4096);
            gl16(bsrc_l + ko, bdst_l + (p ^ 1) * 4096);
        }
        const u16* Bb = &Bst[p][0][0][0];
#pragma unroll
        for (int sub = 0; sub < 2; ++sub) {
            const int kc = ph * 2 + sub;
            const bf16x8 A  = *(const bf16x8*)&ah[kc * 32];
            const bf16x8 Al = *(const bf16x8*)&al[kc * 32];
#pragma unroll
            for (int nf = 0; nf < 2; ++nf) {
                const int r = nf * 16 + mcol;
                const int g = (sub * 4 + quad) ^ (r & 7);
                const bf16x8 Bh = *(const bf16x8*)&Bb[r * 64 + g * 8];
                const bf16x8 Bl = *(const bf16x8*)&Bb[2048 + r * 64 + g * 8];
                c[nf] = __builtin_amdgcn_mfma_f32_16x16x32_bf16(A,  Bh, c[nf], 0, 0, 0);
                c[nf] = __builtin_amdgcn_mfma_f32_16x16x32_bf16(A,  Bl, c[nf], 0, 0, 0);
                c[nf] = __builtin_amdgcn_mfma_f32_16x16x32_bf16(Al, Bh, c[nf], 0, 0, 0);
            }
        }
        p ^= 1;
    }
    float* ob = out + ((size_t)b * CC + c0 + w * 16) * NPOS + j0;
#pragma unroll
    for (int nf = 0; nf < 2; ++nf)
#pragma unroll
        for (int r = 0; r < 4; ++r)
            ob[(size_t)(quad * 4 + r) * NPOS + nf * 16 + mcol] = c[nf][r];
}

extern "C" void kernel_launch(void* const* d_in, const int* in_sizes, int n_in,
                              void* d_out, int out_size, void* d_ws, size_t ws_size,
                              hipStream_t stream) {
    const float* fmap    = (const float*)d_in[0];
    const float* gamma   = (const float*)d_in[1];
    const float* w_qk    = (const float*)d_in[2];
    const float* w_v     = (const float*)d_in[3];
    const float* null_kv = (const float*)d_in[4];
    const float* w_out   = (const float*)d_in[5];
    float* out = (float*)d_out;

    u16* ws16 = (u16*)d_ws;
    u16* qkh    = ws16;                     // 16*2304*64  = 2,359,296 u16
    u16* vtb    = qkh + 2359296;            // 16*72*64*32 = 2,359,296
    u16* in_hi  = vtb + 2359296;            // 2*2304*512  = 2,359,296
    u16* in_lo  = in_hi + 2359296;          //               2,359,296
    u16* wo_hi  = in_lo + 2359296;          // 256*512     =   131,072
    u16* wo_lo  = wo_hi + 131072;           //                 131,072
    u16* wqkh   = wo_lo + 131072;           // 512*256     =   131,072
    u16* wvh    = wqkh + 131072;            //                 131,072
    float* sqbuf = (float*)(wvh + 131072);      // 36,864 f32
    float* ndbuf = sqbuf + 36864;               // 36,864
    float* nk2b  = ndbuf + 36864;               // 8
    // base total ~20.2 MB; k-split partials below need +19.2 MB
    float* pOws  = nk2b + 8;                    // 2*16*2304*64 = 4,718,592 f32
    float* pLws  = pOws + 4718592;              // 2*16*2304    =    73,728 f32
    const size_t need_split = (size_t)((char*)(pLws + 73728) - (char*)d_ws);

    hipLaunchKernelGGL(k_prep, dim3(384),       dim3(256), 0, stream,
                       w_qk, w_v, w_out, wqkh, wvh, wo_hi, wo_lo);
    hipLaunchKernelGGL(k_proj, dim3(576),       dim3(256), 0, stream,
                       fmap, gamma, wqkh, wvh, null_kv, qkh, vtb, sqbuf, ndbuf, nk2b);
    if (ws_size >= need_split) {
        hipLaunchKernelGGL(HIP_KERNEL_NAME(k_attn<2>), dim3(1152), dim3(256), 0, stream,
                           qkh, vtb, null_kv, nk2b, sqbuf, ndbuf, in_hi, in_lo, pOws, pLws);
        hipLaunchKernelGGL(k_merge, dim3(576),  dim3(256), 0, stream,
                           pOws, pLws, null_kv, nk2b, sqbuf, ndbuf, in_hi, in_lo);
    } else {
        hipLaunchKernelGGL(HIP_KERNEL_NAME(k_attn<1>), dim3(576), dim3(256), 0, stream,
                           qkh, vtb, null_kv, nk2b, sqbuf, ndbuf, in_hi, in_lo, pOws, pLws);
    }
    hipLaunchKernelGGL(k_out,  dim3(72, 4, 2),  dim3(256), 0, stream,
                       wo_hi, wo_lo, in_hi, in_lo, out);
}